// Round 1
// baseline (1744.926 us; speedup 1.0000x reference)
//
#include <hip/hip_runtime.h>

typedef unsigned int u32;
typedef unsigned short u16;

namespace {

constexpr int TT  = 256;           // T (frames == BN channels)
constexpr int VV  = 90;            // joints
constexpr int BTV = TT * VV;       // 23040
constexpr int NB  = 1024;          // batch

// ---- LDS pool (float offsets) ----
constexpr int ET_S = 130;          // E_t row stride (pad vs bank conflicts)
constexpr int PH_S = 92;           // phi row stride (16B-alignable, odd/4 pattern ok)
constexpr int TQ_S = 92;           // theta/g chunk row stride
constexpr int ES_S = 91;           // E_s row stride

constexpr int OFF_ET  = 0;                     // [128][130] = 16640 fl
constexpr int OFF_PHI = 16640;                 // [128][92]  = 11776 fl  (later E_s [90][91]=8190)
constexpr int OFF_TQ  = OFF_PHI + 11776;       // 28416: [64][92] = 5888 fl
constexpr int OFF_XT  = OFF_TQ + 5888;         // 34304: [16][96] = 1536 fl
constexpr int OFF_SM  = OFF_XT + 1536;         // 35840
constexpr int SM_WORDS = 4096;
constexpr int SMEM_FL  = OFF_SM + SM_WORDS;    // 39936
constexpr int SMEM_BYTES = SMEM_FL * 4;        // 159744 (<163840)

// small-area offsets (relative to OFF_SM)
constexpr int sS_G = 0, sS_TH = 256, sS_PH = 512, sS_W = 768;
constexpr int sD_G = 1024, sD_TH = 1280, sD_PH = 1536;
constexpr int sBE_G = 1792, sBE_TH = 1920, sBE_PH = 2048;
constexpr int sBW_E = 2176;        // 256
constexpr int sX1MV = 2432;        // 256
constexpr int sX2MT = 2688;        // 96
constexpr int sETRM = 2784, sETRS = 2912, sETCM = 3040, sETCS = 3168; // 128 each
constexpr int sESRM = 3296, sESRS = 3392, sESCM = 3488, sESCS = 3584; // 96 each
constexpr int sCSW = 3680;         // 128
constexpr int sZR1 = 3808, sZR2 = 3936;
constexpr int sSCAL = 4064;        // 0:mean1 1:mean2 2:bwsum 3..5:w1 6..8:w2

#define SMF(o) sm[OFF_SM + (o)]

__device__ __forceinline__ float bflo(u32 u){ return __uint_as_float(u << 16); }
__device__ __forceinline__ float bfhi(u32 u){ return __uint_as_float(u & 0xFFFF0000u); }
__device__ __forceinline__ u16 f2bf(float x){
  u32 u = __float_as_uint(x);
  u += 0x7FFFu + ((u >> 16) & 1u);         // RNE
  return (u16)(u >> 16);
}
__device__ __forceinline__ float bf2f(u16 h){ return __uint_as_float(((u32)h) << 16); }
__device__ __forceinline__ float d4(float4 a, float4 b){
  return a.x*b.x + a.y*b.y + a.z*b.z + a.w*b.w;
}

// out rows [rowBase, rowBase+64): out[co][v] = sum_t w[(rowBase+co)*256+t]*s[t]*x[t*90+v] + b[rowBase+co]
// all 512 threads participate; contains internal barriers; caller barriers after.
__device__ void gemm64(float* __restrict__ out, const float* __restrict__ xg,
                       const float* __restrict__ wg, int rowBase,
                       const float* __restrict__ sArr, const float* __restrict__ bArr,
                       float* __restrict__ xt, int tid)
{
  const int co = tid >> 3;
  const int v0 = 12 * (tid & 7);
  float acc[12];
#pragma unroll
  for (int j = 0; j < 12; ++j) acc[j] = 0.f;
  const float* wrow = wg + (rowBase + co) * TT;
  for (int kt = 0; kt < 16; ++kt){
#pragma unroll
    for (int s = 0; s < 3; ++s){
      int idx = tid + 512 * s;
      int r = idx / 96;
      int vv = idx - r * 96;
      xt[idx] = (vv < VV) ? xg[(kt * 16 + r) * VV + vv] : 0.f;
    }
    __syncthreads();
#pragma unroll
    for (int r = 0; r < 16; ++r){
      float wvv = wrow[kt * 16 + r] * sArr[kt * 16 + r];
      const float4* xp = (const float4*)(xt + r * 96 + v0);
      float xv[12];
#pragma unroll
      for (int q = 0; q < 3; ++q) ((float4*)xv)[q] = xp[q];
#pragma unroll
      for (int j = 0; j < 12; ++j) acc[j] += wvv * xv[j];
    }
    __syncthreads();
  }
  float bb = bArr[rowBase + co];
#pragma unroll
  for (int j = 0; j < 12; ++j){
    int v = v0 + j;
    if (v < VV) out[co * TQ_S + v] = acc[j] + bb;
  }
}

// full 128 rows (phi)
__device__ void gemm128(float* __restrict__ out, const float* __restrict__ xg,
                        const float* __restrict__ wg,
                        const float* __restrict__ sArr, const float* __restrict__ bArr,
                        float* __restrict__ xt, int tid)
{
  const int co = tid >> 2;
  const int v0 = 24 * (tid & 3);
  float acc[24];
#pragma unroll
  for (int j = 0; j < 24; ++j) acc[j] = 0.f;
  const float* wrow = wg + co * TT;
  for (int kt = 0; kt < 16; ++kt){
#pragma unroll
    for (int s = 0; s < 3; ++s){
      int idx = tid + 512 * s;
      int r = idx / 96;
      int vv = idx - r * 96;
      xt[idx] = (vv < VV) ? xg[(kt * 16 + r) * VV + vv] : 0.f;
    }
    __syncthreads();
#pragma unroll
    for (int r = 0; r < 16; ++r){
      float wvv = wrow[kt * 16 + r] * sArr[kt * 16 + r];
      const float4* xp = (const float4*)(xt + r * 96 + v0);
      float xv[24];
#pragma unroll
      for (int q = 0; q < 6; ++q) ((float4*)xv)[q] = xp[q];
#pragma unroll
      for (int j = 0; j < 24; ++j) acc[j] += wvv * xv[j];
    }
    __syncthreads();
  }
  float bb = bArr[co];
#pragma unroll
  for (int j = 0; j < 24; ++j){
    int v = v0 + j;
    if (v < VV) out[co * PH_S + v] = acc[j] + bb;
  }
}

__global__ __launch_bounds__(512, 1)
void stacif_fused(
    const float* __restrict__ x1g, const float* __restrict__ x2g,
    const float* __restrict__ g_bng, const float* __restrict__ g_bnb,
    const float* __restrict__ g_bnm, const float* __restrict__ g_bnv,
    const float* __restrict__ g_w,  const float* __restrict__ g_b,
    const float* __restrict__ th_bng, const float* __restrict__ th_bnb,
    const float* __restrict__ th_bnm, const float* __restrict__ th_bnv,
    const float* __restrict__ th_w, const float* __restrict__ th_b,
    const float* __restrict__ ph_bng, const float* __restrict__ ph_bnb,
    const float* __restrict__ ph_bnm, const float* __restrict__ ph_bnv,
    const float* __restrict__ ph_w, const float* __restrict__ ph_b,
    const float* __restrict__ W_w,  const float* __restrict__ W_b,
    const float* __restrict__ W_bng, const float* __restrict__ W_bnb,
    const float* __restrict__ W_bnm, const float* __restrict__ W_bnv,
    float* __restrict__ outg)
{
  extern __shared__ float sm[];
  const int tid = threadIdx.x;
  const int bid = blockIdx.x;
  const float* __restrict__ x1b = x1g + (size_t)bid * BTV;
  const float* __restrict__ x2b = x2g + (size_t)bid * BTV;
  float* xt = sm + OFF_XT;

  // -------- zero small area --------
  for (int i = tid; i < SM_WORDS; i += 512) sm[OFF_SM + i] = 0.f;
  __syncthreads();

  // -------- fold BN into conv scale/shift --------
  if (tid < 256){
    int t = tid;
    float sg = g_bng[t]  * rsqrtf(g_bnv[t]  + 1e-5f);
    float st = th_bng[t] * rsqrtf(th_bnv[t] + 1e-5f);
    float sp = ph_bng[t] * rsqrtf(ph_bnv[t] + 1e-5f);
    float sw = W_bng[t]  * rsqrtf(W_bnv[t]  + 1e-5f);
    SMF(sS_G  + t) = sg;  SMF(sD_G  + t) = g_bnb[t]  - g_bnm[t]  * sg;
    SMF(sS_TH + t) = st;  SMF(sD_TH + t) = th_bnb[t] - th_bnm[t] * st;
    SMF(sS_PH + t) = sp;  SMF(sD_PH + t) = ph_bnb[t] - ph_bnm[t] * sp;
    SMF(sS_W  + t) = sw;  SMF(sBW_E + t) = (W_b[t] - W_bnm[t]) * sw + W_bnb[t];
  }
  __syncthreads();
  if (tid < 128){
    int c = tid; float a = 0.f;
    for (int t = 0; t < 256; ++t) a += g_w[c*256+t] * SMF(sD_G + t);
    SMF(sBE_G + c) = g_b[c] + a;
  } else if (tid < 256){
    int c = tid - 128; float a = 0.f;
    for (int t = 0; t < 256; ++t) a += th_w[c*256+t] * SMF(sD_TH + t);
    SMF(sBE_TH + c) = th_b[c] + a;
  } else if (tid < 384){
    int c = tid - 256; float a = 0.f;
    for (int t = 0; t < 256; ++t) a += ph_w[c*256+t] * SMF(sD_PH + t);
    SMF(sBE_PH + c) = ph_b[c] + a;
  } else if (tid == 384){
    float a = 0.f;
    for (int t = 0; t < 256; ++t) a += SMF(sBW_E + t);
    SMF(sSCAL + 2) = a;
  }
  __syncthreads();

  // -------- means: x1 row-means (over V), x2 col-means (over T) --------
  {
    int wid = tid >> 6, lane = tid & 63;
    for (int t = wid; t < 256; t += 8){
      float s = x1b[t*VV + lane];
      if (lane < 26) s += x1b[t*VV + 64 + lane];
#pragma unroll
      for (int off = 32; off > 0; off >>= 1) s += __shfl_down(s, off);
      if (lane == 0) SMF(sX1MV + t) = s * (1.f/90.f);
    }
  }
  if (tid < 450){
    int v = tid % 90, tc = tid / 90;
    int t0 = tc * 52, t1 = t0 + 52; if (t1 > 256) t1 = 256;
    float s = 0.f;
    for (int t = t0; t < t1; ++t) s += x2b[t*VV + v];
    atomicAdd(&SMF(sX2MT + v), s);
  }
  __syncthreads();
  if (tid < 90) SMF(sX2MT + tid) *= (1.f/256.f);
  __syncthreads();
  if (tid == 0){
    float a = 0.f;
    for (int t = 0; t < 256; ++t) a += SMF(sX1MV + t);
    SMF(sSCAL + 0) = a * (1.f/256.f);
  }
  if (tid == 1){
    float a = 0.f;
    for (int v = 0; v < 90; ++v) a += SMF(sX2MT + v);
    SMF(sSCAL + 1) = a * (1.f/90.f);
  }
  __syncthreads();

  // -------- P1: phi = ph'(x2)  (full 128 rows in LDS) --------
  gemm128(sm + OFF_PHI, x2b, ph_w, sm+OFF_SM+sS_PH, sm+OFF_SM+sBE_PH, xt, tid);
  __syncthreads();

  // -------- P2: theta in 2 chunks of 64 rows; E_t rows; E_s accumulated in regs --------
  float es[18];
#pragma unroll
  for (int i = 0; i < 18; ++i) es[i] = 0.f;
  const int esv0 = 6 * (tid / 30);
  const int esw0 = 3 * (tid - (tid / 30) * 30);
  const bool esAct = (tid < 450);

  for (int ch = 0; ch < 2; ++ch){
    gemm64(sm + OFF_TQ, x1b, th_w, 64*ch, sm+OFF_SM+sS_TH, sm+OFF_SM+sBE_TH, xt, tid);
    __syncthreads();
    { // E_t rows [64ch, 64ch+64): E_t[c,d] = sum_v theta[c,v]*phi[d,v]
      const int aa = tid >> 5, mm = tid & 31;
      const float* thp = sm + OFF_TQ;
      const float* php = sm + OFF_PHI;
      float et[16];
#pragma unroll
      for (int i = 0; i < 16; ++i) et[i] = 0.f;
      for (int v = 0; v < 88; v += 4){
        float4 tv0 = *(const float4*)(thp + (4*aa+0)*TQ_S + v);
        float4 tv1 = *(const float4*)(thp + (4*aa+1)*TQ_S + v);
        float4 tv2 = *(const float4*)(thp + (4*aa+2)*TQ_S + v);
        float4 tv3 = *(const float4*)(thp + (4*aa+3)*TQ_S + v);
        float4 pv0 = *(const float4*)(php + (mm +  0)*PH_S + v);
        float4 pv1 = *(const float4*)(php + (mm + 32)*PH_S + v);
        float4 pv2 = *(const float4*)(php + (mm + 64)*PH_S + v);
        float4 pv3 = *(const float4*)(php + (mm + 96)*PH_S + v);
        et[0]+=d4(tv0,pv0);  et[1]+=d4(tv0,pv1);  et[2]+=d4(tv0,pv2);  et[3]+=d4(tv0,pv3);
        et[4]+=d4(tv1,pv0);  et[5]+=d4(tv1,pv1);  et[6]+=d4(tv1,pv2);  et[7]+=d4(tv1,pv3);
        et[8]+=d4(tv2,pv0);  et[9]+=d4(tv2,pv1);  et[10]+=d4(tv2,pv2); et[11]+=d4(tv2,pv3);
        et[12]+=d4(tv3,pv0); et[13]+=d4(tv3,pv1); et[14]+=d4(tv3,pv2); et[15]+=d4(tv3,pv3);
      }
#pragma unroll
      for (int v = 88; v < 90; ++v){
        float t0_ = thp[(4*aa+0)*TQ_S+v], t1_ = thp[(4*aa+1)*TQ_S+v];
        float t2_ = thp[(4*aa+2)*TQ_S+v], t3_ = thp[(4*aa+3)*TQ_S+v];
        float p0_ = php[(mm+ 0)*PH_S+v], p1_ = php[(mm+32)*PH_S+v];
        float p2_ = php[(mm+64)*PH_S+v], p3_ = php[(mm+96)*PH_S+v];
        et[0]+=t0_*p0_;  et[1]+=t0_*p1_;  et[2]+=t0_*p2_;  et[3]+=t0_*p3_;
        et[4]+=t1_*p0_;  et[5]+=t1_*p1_;  et[6]+=t1_*p2_;  et[7]+=t1_*p3_;
        et[8]+=t2_*p0_;  et[9]+=t2_*p1_;  et[10]+=t2_*p2_; et[11]+=t2_*p3_;
        et[12]+=t3_*p0_; et[13]+=t3_*p1_; et[14]+=t3_*p2_; et[15]+=t3_*p3_;
      }
#pragma unroll
      for (int i = 0; i < 4; ++i)
#pragma unroll
        for (int j = 0; j < 4; ++j)
          sm[OFF_ET + (64*ch + 4*aa + i)*ET_S + (mm + 32*j)] = et[i*4+j];
    }
    if (esAct){ // E_s[v,w] += sum over this chunk's c of theta[c,v]*phi[c,w]
      const float* thp = sm + OFF_TQ;
      const float* php = sm + OFF_PHI;
      for (int cci = 0; cci < 64; ++cci){
        float pw0 = php[(64*ch+cci)*PH_S + esw0 + 0];
        float pw1 = php[(64*ch+cci)*PH_S + esw0 + 1];
        float pw2 = php[(64*ch+cci)*PH_S + esw0 + 2];
#pragma unroll
        for (int i = 0; i < 6; ++i){
          float tv = thp[cci*TQ_S + esv0 + i];
          es[i*3+0] += tv*pw0; es[i*3+1] += tv*pw1; es[i*3+2] += tv*pw2;
        }
      }
    }
    __syncthreads();  // protect thq before next chunk overwrites
  }
  // -------- P3: write E_s (overwrites phi region) --------
  if (esAct){
    float* ES = sm + OFF_PHI;
#pragma unroll
    for (int i = 0; i < 6; ++i)
#pragma unroll
      for (int j = 0; j < 3; ++j)
        ES[(esv0+i)*ES_S + (esw0+j)] = es[i*3+j];
  }
  __syncthreads();

  // -------- P4: softmax stats (store inverse sums) --------
  {
    if (tid < 128){
      int r = tid; const float* p = sm + OFF_ET + r*ET_S;
      float m = -3.0e38f;
      for (int d = 0; d < 128; ++d) m = fmaxf(m, p[d]);
      float s = 0.f;
      for (int d = 0; d < 128; ++d) s += __expf(p[d] - m);
      SMF(sETRM + r) = m; SMF(sETRS + r) = 1.f / s;
    } else if (tid < 256){
      int c = tid - 128; const float* p = sm + OFF_ET + c;
      float m = -3.0e38f;
      for (int d = 0; d < 128; ++d) m = fmaxf(m, p[d*ET_S]);
      float s = 0.f;
      for (int d = 0; d < 128; ++d) s += __expf(p[d*ET_S] - m);
      SMF(sETCM + c) = m; SMF(sETCS + c) = 1.f / s;
    } else if (tid < 346){
      int v = tid - 256; const float* p = sm + OFF_PHI + v*ES_S;
      float m = -3.0e38f;
      for (int w = 0; w < 90; ++w) m = fmaxf(m, p[w]);
      float s = 0.f;
      for (int w = 0; w < 90; ++w) s += __expf(p[w] - m);
      SMF(sESRM + v) = m; SMF(sESRS + v) = 1.f / s;
    } else if (tid < 436){
      int v = tid - 346; const float* p = sm + OFF_PHI + v;
      float m = -3.0e38f;
      for (int w = 0; w < 90; ++w) m = fmaxf(m, p[w*ES_S]);
      float s = 0.f;
      for (int w = 0; w < 90; ++w) s += __expf(p[w*ES_S] - m);
      SMF(sESCM + v) = m; SMF(sESCS + v) = 1.f / s;
    }
  }
  __syncthreads();

  // -------- P5: M1 = AT2 @ g(x1), M2 = AT1 @ g(x2)  (accumulated in regs over 2 chunks) --------
  const int cM  = tid >> 2;
  const int vM0 = 24 * (tid & 3);
  float m1a[24], m2a[24];
#pragma unroll
  for (int j = 0; j < 24; ++j){ m1a[j] = 0.f; m2a[j] = 0.f; }
  for (int gch = 0; gch < 2; ++gch){
    gemm64(sm + OFF_TQ, x1b, g_w, 64*gch, sm+OFF_SM+sS_G, sm+OFF_SM+sBE_G, xt, tid);
    __syncthreads();
    {
      float cmx = SMF(sETCM + cM);
      for (int dd = 0; dd < 64; ++dd){
        int d = 64*gch + dd;
        float e = __expf(sm[OFF_ET + d*ET_S + cM] - cmx);
        const float4* gp = (const float4*)(sm + OFF_TQ + dd*TQ_S + vM0);
        float gv[24];
#pragma unroll
        for (int q = 0; q < 6; ++q) ((float4*)gv)[q] = gp[q];
#pragma unroll
        for (int j = 0; j < 24; ++j) m1a[j] += e * gv[j];
      }
    }
    __syncthreads();
    gemm64(sm + OFF_TQ, x2b, g_w, 64*gch, sm+OFF_SM+sS_G, sm+OFF_SM+sBE_G, xt, tid);
    __syncthreads();
    {
      float rmx = SMF(sETRM + cM);
      for (int dd = 0; dd < 64; ++dd){
        int d = 64*gch + dd;
        float e = __expf(sm[OFF_ET + cM*ET_S + d] - rmx);
        const float4* gp = (const float4*)(sm + OFF_TQ + dd*TQ_S + vM0);
        float gv[24];
#pragma unroll
        for (int q = 0; q < 6; ++q) ((float4*)gv)[q] = gp[q];
#pragma unroll
        for (int j = 0; j < 24; ++j) m2a[j] += e * gv[j];
      }
    }
    __syncthreads();  // also makes E_t reads complete before Mt overwrite below
  }
  {
    float i1 = SMF(sETCS + cM), i2 = SMF(sETRS + cM);
    u16* Mt1 = (u16*)sm;
    u16* Mt2 = Mt1 + 11520;   // [90][128] bf16 each
#pragma unroll
    for (int j = 0; j < 24; ++j){
      int v = vM0 + j;
      if (v < VV){
        Mt1[v*128 + cM] = f2bf(m1a[j] * i1);
        Mt2[v*128 + cM] = f2bf(m2a[j] * i2);
      }
    }
  }
  __syncthreads();

  // -------- P6: z1 = M1 @ AS2 ; z2 = M2 @ AS1 (both in regs, then bf16 [128][96]) --------
  {
    const int wz = tid % 90;
    const int cc = tid / 90;     // active for cc<4 -> c0 = 32*cc
    const bool act = (cc < 4);
    const int c0 = 32 * cc;
    float z1a[32], z2a[32];
#pragma unroll
    for (int k = 0; k < 32; ++k){ z1a[k] = 0.f; z2a[k] = 0.f; }
    const u16* Mt1 = (const u16*)sm;
    const u16* Mt2 = Mt1 + 11520;
    const float* ES = sm + OFF_PHI;
    if (act){
      for (int v = 0; v < 90; ++v){
        float a2 = __expf(ES[v*ES_S + wz] - SMF(sESRM + v)) * SMF(sESRS + v); // AS2[v,wz]
        float a1 = __expf(ES[wz*ES_S + v] - SMF(sESCM + v)) * SMF(sESCS + v); // AS1[v,wz]
        const uint4* q1 = (const uint4*)(Mt1 + v*128 + c0);
        const uint4* q2 = (const uint4*)(Mt2 + v*128 + c0);
#pragma unroll
        for (int q = 0; q < 4; ++q){
          uint4 u = q1[q];
          z1a[q*8+0] += a2*bflo(u.x); z1a[q*8+1] += a2*bfhi(u.x);
          z1a[q*8+2] += a2*bflo(u.y); z1a[q*8+3] += a2*bfhi(u.y);
          z1a[q*8+4] += a2*bflo(u.z); z1a[q*8+5] += a2*bfhi(u.z);
          z1a[q*8+6] += a2*bflo(u.w); z1a[q*8+7] += a2*bfhi(u.w);
        }
#pragma unroll
        for (int q = 0; q < 4; ++q){
          uint4 u = q2[q];
          z2a[q*8+0] += a1*bflo(u.x); z2a[q*8+1] += a1*bfhi(u.x);
          z2a[q*8+2] += a1*bflo(u.y); z2a[q*8+3] += a1*bfhi(u.y);
          z2a[q*8+4] += a1*bflo(u.z); z2a[q*8+5] += a1*bfhi(u.z);
          z2a[q*8+6] += a1*bflo(u.w); z2a[q*8+7] += a1*bfhi(u.w);
        }
      }
    }
    __syncthreads();   // all Mt reads done; safe to overwrite with z
    u16* Z1 = (u16*)sm;
    u16* Z2 = Z1 + 12288;    // [128][96] bf16 each
    if (act){
#pragma unroll
      for (int k = 0; k < 32; ++k){
        Z1[(c0+k)*96 + wz] = f2bf(z1a[k]);
        Z2[(c0+k)*96 + wz] = f2bf(z2a[k]);
      }
    }
    if (tid < 128){
#pragma unroll
      for (int v = 90; v < 96; ++v){ Z1[tid*96+v] = 0; Z2[tid*96+v] = 0; }
    }
  }
  __syncthreads();

  // -------- P7a: stage W' (bf16, transposed [c][t], stride 260) --------
  {
    u16* Wl = (u16*)(sm + 12288);
    for (int i = tid; i < 32768; i += 512){
      int t = i >> 7, c = i & 127;
      Wl[c*260 + t] = f2bf(W_w[i] * SMF(sS_W + t));
    }
  }
  __syncthreads();
  // -------- P7b: reductions for proj means --------
  {
    const u16* Wl = (const u16*)(sm + 12288);
    const u16* Z1 = (const u16*)sm;
    const u16* Z2 = Z1 + 12288;
    if (tid < 128){
      int c = tid; float a = 0.f;
      for (int t = 0; t < 256; ++t) a += bf2f(Wl[c*260 + t]);
      SMF(sCSW + c) = a;
    } else if (tid < 256){
      int c = tid - 128; float a = 0.f;
      for (int v = 0; v < 90; ++v) a += bf2f(Z1[c*96 + v]);
      SMF(sZR1 + c) = a;
    } else if (tid < 384){
      int c = tid - 256; float a = 0.f;
      for (int v = 0; v < 90; ++v) a += bf2f(Z2[c*96 + v]);
      SMF(sZR2 + c) = a;
    }
  }
  __syncthreads();
  if (tid == 0){
    float s1 = 0.f, s2 = 0.f;
    for (int c = 0; c < 128; ++c){
      s1 += SMF(sCSW+c) * SMF(sZR1+c);
      s2 += SMF(sCSW+c) * SMF(sZR2+c);
    }
    float bws = SMF(sSCAL + 2);
    float mp1 = (s1 + 90.f*bws) * (1.f/23040.f);
    float mp2 = (s2 + 90.f*bws) * (1.f/23040.f);
    float m1v = SMF(sSCAL + 0), m2v = SMF(sSCAL + 1);
    {
      float mx = fmaxf(m1v, fmaxf(m2v, mp1));
      float e0 = __expf(m1v-mx), e1 = __expf(m2v-mx), e2 = __expf(mp1-mx);
      float inv = 1.f/(e0+e1+e2);
      SMF(sSCAL+3) = e0*inv; SMF(sSCAL+4) = e1*inv; SMF(sSCAL+5) = e2*inv;
    }
    {
      float mx = fmaxf(m2v, fmaxf(m1v, mp2));
      float e0 = __expf(m2v-mx), e1 = __expf(m1v-mx), e2 = __expf(mp2-mx);
      float inv = 1.f/(e0+e1+e2);
      SMF(sSCAL+6) = e0*inv; SMF(sSCAL+7) = e1*inv; SMF(sSCAL+8) = e2*inv;
    }
  }
  __syncthreads();

  // -------- P7c: proj GEMM + fused outputs --------
  {
    const u16* Wl = (const u16*)(sm + 12288);
    const u16* Z1 = (const u16*)sm;
    const u16* Z2 = Z1 + 12288;
    const int ttb = tid >> 3;          // 0..63 -> t = 4*ttb + k
    const int vb  = 12 * (tid & 7);    // v = vb + j
    float p1[48], p2[48];
#pragma unroll
    for (int i = 0; i < 48; ++i){ p1[i] = 0.f; p2[i] = 0.f; }
    for (int c = 0; c < 128; ++c){
      uint2 wu = *(const uint2*)(Wl + c*260 + 4*ttb);
      float wf0 = bflo(wu.x), wf1 = bfhi(wu.x), wf2 = bflo(wu.y), wf3 = bfhi(wu.y);
      const u32* z1p = (const u32*)(Z1 + c*96 + vb);
      const u32* z2p = (const u32*)(Z2 + c*96 + vb);
      float zf1[12], zf2[12];
#pragma unroll
      for (int q = 0; q < 6; ++q){
        u32 ua = z1p[q]; zf1[2*q] = bflo(ua); zf1[2*q+1] = bfhi(ua);
        u32 ub = z2p[q]; zf2[2*q] = bflo(ub); zf2[2*q+1] = bfhi(ub);
      }
#pragma unroll
      for (int j = 0; j < 12; ++j){
        p1[0*12+j] += wf0*zf1[j]; p1[1*12+j] += wf1*zf1[j];
        p1[2*12+j] += wf2*zf1[j]; p1[3*12+j] += wf3*zf1[j];
        p2[0*12+j] += wf0*zf2[j]; p2[1*12+j] += wf1*zf2[j];
        p2[2*12+j] += wf2*zf2[j]; p2[3*12+j] += wf3*zf2[j];
      }
    }
    float w10 = SMF(sSCAL+3), w11 = SMF(sSCAL+4), w12 = SMF(sSCAL+5);
    float w20 = SMF(sSCAL+6), w21 = SMF(sSCAL+7), w22 = SMF(sSCAL+8);
    float* out1 = outg + (size_t)bid * BTV;
    float* out2 = outg + (size_t)NB * BTV + (size_t)bid * BTV;
#pragma unroll
    for (int k = 0; k < 4; ++k){
      int t = 4*ttb + k;
      float bw  = SMF(sBW_E + t);
      float x1m = SMF(sX1MV + t);
#pragma unroll
      for (int j = 0; j < 12; ++j){
        int v = vb + j;
        if (v < VV){
          out1[t*VV + v] = w10 * x1b[t*VV + v] + w11 * SMF(sX2MT + v) + w12 * (p1[k*12+j] + bw);
          out2[t*VV + v] = w20 * x2b[t*VV + v] + w21 * x1m            + w22 * (p2[k*12+j] + bw);
        }
      }
    }
  }
}

} // namespace

extern "C" void kernel_launch(void* const* d_in, const int* in_sizes, int n_in,
                              void* d_out, int out_size, void* d_ws, size_t ws_size,
                              hipStream_t stream)
{
  (void)in_sizes; (void)n_in; (void)d_ws; (void)ws_size; (void)out_size;
  // allow >64KB dynamic LDS (gfx950: up to 160KB/WG). Idempotent, deterministic.
  hipFuncSetAttribute((const void*)stacif_fused,
                      hipFuncAttributeMaxDynamicSharedMemorySize, SMEM_BYTES);

  const float* x1   = (const float*)d_in[0];
  const float* x2   = (const float*)d_in[1];
  const float* g_bng = (const float*)d_in[2];
  const float* g_bnb = (const float*)d_in[3];
  const float* g_bnm = (const float*)d_in[4];
  const float* g_bnv = (const float*)d_in[5];
  const float* g_w   = (const float*)d_in[6];
  const float* g_b   = (const float*)d_in[7];
  const float* th_bng = (const float*)d_in[8];
  const float* th_bnb = (const float*)d_in[9];
  const float* th_bnm = (const float*)d_in[10];
  const float* th_bnv = (const float*)d_in[11];
  const float* th_w   = (const float*)d_in[12];
  const float* th_b   = (const float*)d_in[13];
  const float* ph_bng = (const float*)d_in[14];
  const float* ph_bnb = (const float*)d_in[15];
  const float* ph_bnm = (const float*)d_in[16];
  const float* ph_bnv = (const float*)d_in[17];
  const float* ph_w   = (const float*)d_in[18];
  const float* ph_b   = (const float*)d_in[19];
  const float* W_w    = (const float*)d_in[20];
  const float* W_b    = (const float*)d_in[21];
  const float* W_bng  = (const float*)d_in[22];
  const float* W_bnb  = (const float*)d_in[23];
  const float* W_bnm  = (const float*)d_in[24];
  const float* W_bnv  = (const float*)d_in[25];
  float* out = (float*)d_out;

  stacif_fused<<<dim3(NB), dim3(512), SMEM_BYTES, stream>>>(
      x1, x2,
      g_bng, g_bnb, g_bnm, g_bnv, g_w, g_b,
      th_bng, th_bnb, th_bnm, th_bnv, th_w, th_b,
      ph_bng, ph_bnb, ph_bnm, ph_bnv, ph_w, ph_b,
      W_w, W_b, W_bng, W_bnb, W_bnm, W_bnv,
      out);
}

// Round 4
// 545.508 us; speedup vs baseline: 3.1987x; 3.1987x over previous
//
#include <hip/hip_runtime.h>

typedef unsigned int u32;
typedef _Float16 f16;
typedef short s16;
typedef _Float16 f16x8 __attribute__((ext_vector_type(8)));
typedef short bf16x8 __attribute__((ext_vector_type(8)));
typedef float f32x4 __attribute__((ext_vector_type(4)));

#define MFMA16(a,b,c) __builtin_amdgcn_mfma_f32_16x16x32_f16(a,b,c,0,0,0)
#define MFMABF(a,b,c) __builtin_amdgcn_mfma_f32_16x16x32_bf16(a,b,c,0,0,0)

namespace {

constexpr int VV = 90, BTV = 256*90, NB = 1024;

// ---- LDS layout (2-byte-element offsets) ----
constexpr int XT  = 0;         // f16 [96][272] staging x1T / x2T
constexpr int UT  = 0;         // bf16 [128][136] exp(Et - rowmax)   (after staging dead)
constexpr int US  = 17408;     // bf16 [90][96]   exp(Es - rowmax)
constexpr int G1T = 26112;     // bf16 [96][136]
constexpr int THT = 39168;     // f16 [96][136]
constexpr int PHT = 52224;     // f16 [96][136]
constexpr int G2T = 65280;     // bf16 [96][136]  (ends 78336)
constexpr int M1o = 39168;     // bf16 [128][96]  over THT
constexpr int M2o = 51456;     // bf16 [128][96]
constexpr int Z1o = 26112;     // bf16 [96][136]  over G1T
constexpr int Z2o = 65280;     // bf16 [96][136]  over G2T
constexpr int SBASE = 78336;   // f32 stats area starts here (byte 156672)
constexpr int oX1MV=0, oX2MT=256, oMRT=352, oISRT=480, oMCT=608, oISCT=736,
              oMRS=864, oISRS=960, oMCS=1056, oISCS=1152, oRED1=1248, oRED2=1376, oSCAL=1504;
constexpr int SWORDS = 1520;
constexpr int SMEM_BYTES = SBASE*2 + SWORDS*4;   // 162752 <= 163840

// ---- ws layout (bytes) ----
constexpr size_t wThP=0, wGP=65536, wPhP=131072, wWP=196608,
  wBeTh=262144, wBeG=262656, wBePh=263168, wBwe=263680, wCsw=264704, wBwsum=265216;

__device__ __forceinline__ f16x8 frag_ld(const f16* p, int stride){
  int l = threadIdx.x & 63;
  return *(const f16x8*)(p + (l & 15) * stride + (l >> 4) * 8);
}
__device__ __forceinline__ bf16x8 bfrag_ld(const s16* p, int stride){
  int l = threadIdx.x & 63;
  return *(const bf16x8*)(p + (l & 15) * stride + (l >> 4) * 8);
}
__device__ __forceinline__ s16 f2bf(float x){
  u32 u = __float_as_uint(x);
  u += 0x7FFFu + ((u >> 16) & 1u);   // RNE
  return (s16)(u >> 16);
}
__device__ __forceinline__ float bf2f(s16 h){
  return __uint_as_float(((u32)(unsigned short)h) << 16);
}

// =================== prep kernels ===================
__global__ void prep_weights(
    const float* __restrict__ th_w, const float* __restrict__ th_b,
    const float* __restrict__ th_bng, const float* __restrict__ th_bnb,
    const float* __restrict__ th_bnm, const float* __restrict__ th_bnv,
    const float* __restrict__ g_w, const float* __restrict__ g_b,
    const float* __restrict__ g_bng, const float* __restrict__ g_bnb,
    const float* __restrict__ g_bnm, const float* __restrict__ g_bnv,
    const float* __restrict__ ph_w, const float* __restrict__ ph_b,
    const float* __restrict__ ph_bng, const float* __restrict__ ph_bnb,
    const float* __restrict__ ph_bnm, const float* __restrict__ ph_bnv,
    const float* __restrict__ W_w, const float* __restrict__ W_b,
    const float* __restrict__ W_bng, const float* __restrict__ W_bnb,
    const float* __restrict__ W_bnm, const float* __restrict__ W_bnv,
    char* __restrict__ ws)
{
  __shared__ float red[256];
  const int b = blockIdx.x, tid = threadIdx.x;
  f16* ThP = (f16*)(ws + wThP); f16* GP = (f16*)(ws + wGP);
  f16* PhP = (f16*)(ws + wPhP); s16* WP = (s16*)(ws + wWP);
  float* beTh = (float*)(ws + wBeTh); float* beG = (float*)(ws + wBeG);
  float* bePh = (float*)(ws + wBePh); float* bwe = (float*)(ws + wBwe);
  if (b < 128){
    const int c = b, t = tid;
    {
      float s = th_bng[t] * rsqrtf(th_bnv[t] + 1e-5f);
      float d = th_bnb[t] - th_bnm[t] * s;
      float w = th_w[c*256 + t];
      ThP[c*256 + t] = (f16)(w * s);
      red[tid] = w * d; __syncthreads();
      for (int o = 128; o > 0; o >>= 1){ if (tid < o) red[tid] += red[tid+o]; __syncthreads(); }
      if (tid == 0) beTh[c] = th_b[c] + red[0];
      __syncthreads();
    }
    {
      float s = g_bng[t] * rsqrtf(g_bnv[t] + 1e-5f);
      float d = g_bnb[t] - g_bnm[t] * s;
      float w = g_w[c*256 + t];
      GP[c*256 + t] = (f16)(w * s);
      red[tid] = w * d; __syncthreads();
      for (int o = 128; o > 0; o >>= 1){ if (tid < o) red[tid] += red[tid+o]; __syncthreads(); }
      if (tid == 0) beG[c] = g_b[c] + red[0];
      __syncthreads();
    }
    {
      float s = ph_bng[t] * rsqrtf(ph_bnv[t] + 1e-5f);
      float d = ph_bnb[t] - ph_bnm[t] * s;
      float w = ph_w[c*256 + t];
      PhP[c*256 + t] = (f16)(w * s);
      red[tid] = w * d; __syncthreads();
      for (int o = 128; o > 0; o >>= 1){ if (tid < o) red[tid] += red[tid+o]; __syncthreads(); }
      if (tid == 0) bePh[c] = ph_b[c] + red[0];
    }
  } else {
    const int t = (b - 128) * 2 + (tid >> 7);
    const int c = tid & 127;
    float s = W_bng[t] * rsqrtf(W_bnv[t] + 1e-5f);
    WP[t*128 + c] = f2bf(W_w[t*128 + c] * s);
    if (c == 0) bwe[t] = (W_b[t] - W_bnm[t]) * s + W_bnb[t];
  }
}

__global__ void prep_scalars(
    const float* __restrict__ W_w,
    const float* __restrict__ W_bng, const float* __restrict__ W_bnv,
    char* __restrict__ ws)
{
  const int tid = threadIdx.x;
  float* csw = (float*)(ws + wCsw); float* bwsum = (float*)(ws + wBwsum);
  const float* bwe = (const float*)(ws + wBwe);
  if (tid < 128){
    float a = 0.f;
    for (int t = 0; t < 256; ++t){
      float s = W_bng[t] * rsqrtf(W_bnv[t] + 1e-5f);
      a += W_w[t*128 + tid] * s;
    }
    csw[tid] = a;
  } else if (tid == 128){
    float a = 0.f;
    for (int t = 0; t < 256; ++t) a += bwe[t];
    bwsum[0] = a;
  }
}

// =================== main kernel ===================
__global__ __launch_bounds__(512, 1)
void stacif_main(const float* __restrict__ x1g, const float* __restrict__ x2g,
                 const char* __restrict__ ws, float* __restrict__ outg)
{
  extern __shared__ f16 sm[];
  float* Sf = (float*)(sm + SBASE);
  const int tid = threadIdx.x, bid = blockIdx.x;
  const int wid = tid >> 6, l = tid & 63;
  const float* __restrict__ x1b = x1g + (size_t)bid * BTV;
  const float* __restrict__ x2b = x2g + (size_t)bid * BTV;
  const f16* ThP = (const f16*)(ws + wThP);
  const f16* GP  = (const f16*)(ws + wGP);
  const f16* PhP = (const f16*)(ws + wPhP);
  const s16* WP  = (const s16*)(ws + wWP);
  const float* beTh = (const float*)(ws + wBeTh);
  const float* beG  = (const float*)(ws + wBeG);
  const float* bePh = (const float*)(ws + wBePh);
  const float* bwe  = (const float*)(ws + wBwe);
  const float* csw  = (const float*)(ws + wCsw);
  const float* bwsum = (const float*)(ws + wBwsum);
  s16* Up  = (s16*)(sm + UT);
  s16* USp = (s16*)(sm + US);

  // ---------- Ph0: stage x1^T ----------
  for (int i = tid; i < BTV; i += 512){
    int t = i / 90, v = i - t * 90;
    sm[XT + v*272 + t] = (f16)x1b[i];
  }
  __syncthreads();

  // ---------- Ph1: x1 row means (over v) + projections thetaT (f16), g1T (bf16) ----------
  if (tid < 256){
    float a = 0.f;
    for (int v = 0; v < 90; ++v) a += (float)sm[XT + v*272 + tid];
    Sf[oX1MV + tid] = a * (1.f/90.f);
  }
  for (int h = 0; h < 3; ++h){
    int hs = wid*3 + h;
    int mat = hs >= 12;
    int rem = mat ? hs - 12 : hs;
    int v0 = (rem >> 1) * 16, c0 = (rem & 1) * 64;
    const f16* Wm = mat ? GP : ThP;
    const float* beg = mat ? beG : beTh;
    f32x4 acc[4] = {};
    for (int kk = 0; kk < 8; ++kk){
      int k0 = kk * 32;
      f16x8 a = frag_ld(sm + XT + v0*272 + k0, 272);
      #pragma unroll
      for (int j = 0; j < 4; ++j){
        f16x8 b = frag_ld(Wm + (c0 + j*16)*256 + k0, 256);
        acc[j] = MFMA16(a, b, acc[j]);
      }
    }
    int vr = v0 + (l >> 4) * 4;
    #pragma unroll
    for (int j = 0; j < 4; ++j){
      int c = c0 + j*16 + (l & 15);
      float bias = beg[c];
      #pragma unroll
      for (int r = 0; r < 4; ++r){
        int v = vr + r;
        float val = acc[j][r] + bias;
        if (mat){
          ((s16*)(sm + G1T))[v*136 + c] = (v < VV) ? f2bf(val) : (s16)0;
        } else {
          sm[THT + v*136 + c] = (v < VV) ? (f16)val : (f16)0.0f;
        }
      }
    }
  }
  __syncthreads();

  // ---------- Ph2: stage x2^T ----------
  for (int i = tid; i < BTV; i += 512){
    int t = i / 90, v = i - t * 90;
    sm[XT + v*272 + t] = (f16)x2b[i];
  }
  __syncthreads();

  // ---------- Ph3: x2 col means (over t) + projections phiT (f16), g2T (bf16) ----------
  if (tid < 90){
    float a = 0.f;
    for (int t = 0; t < 256; ++t) a += (float)sm[XT + tid*272 + t];
    Sf[oX2MT + tid] = a * (1.f/256.f);
  }
  for (int h = 0; h < 3; ++h){
    int hs = wid*3 + h;
    int mat = hs >= 12;
    int rem = mat ? hs - 12 : hs;
    int v0 = (rem >> 1) * 16, c0 = (rem & 1) * 64;
    const f16* Wm = mat ? GP : PhP;
    const float* beg = mat ? beG : bePh;
    f32x4 acc[4] = {};
    for (int kk = 0; kk < 8; ++kk){
      int k0 = kk * 32;
      f16x8 a = frag_ld(sm + XT + v0*272 + k0, 272);
      #pragma unroll
      for (int j = 0; j < 4; ++j){
        f16x8 b = frag_ld(Wm + (c0 + j*16)*256 + k0, 256);
        acc[j] = MFMA16(a, b, acc[j]);
      }
    }
    int vr = v0 + (l >> 4) * 4;
    #pragma unroll
    for (int j = 0; j < 4; ++j){
      int c = c0 + j*16 + (l & 15);
      float bias = beg[c];
      #pragma unroll
      for (int r = 0; r < 4; ++r){
        int v = vr + r;
        float val = acc[j][r] + bias;
        if (mat){
          ((s16*)(sm + G2T))[v*136 + c] = (v < VV) ? f2bf(val) : (s16)0;
        } else {
          sm[PHT + v*136 + c] = (v < VV) ? (f16)val : (f16)0.0f;
        }
      }
    }
  }
  __syncthreads();

  // ---------- Ph4: E_t = theta @ phi^T (f16 MFMA); row stats; U = exp(Et-rowmax) bf16 ----------
  {
    int c0 = wid * 16;
    int ca = c0 + (l & 15);
    f32x4 acc[8] = {};
    for (int kk = 0; kk < 3; ++kk){
      int vb = kk*32 + (l >> 4) * 8;
      f16x8 a;
      #pragma unroll
      for (int b = 0; b < 8; ++b) a[b] = sm[THT + (vb + b)*136 + ca];
      #pragma unroll
      for (int dt = 0; dt < 8; ++dt){
        int da = dt*16 + (l & 15);
        f16x8 bf;
        #pragma unroll
        for (int b = 0; b < 8; ++b) bf[b] = sm[PHT + (vb + b)*136 + da];
        acc[dt] = MFMA16(a, bf, acc[dt]);
      }
    }
    #pragma unroll
    for (int r = 0; r < 4; ++r){
      float m = -3e38f;
      #pragma unroll
      for (int dt = 0; dt < 8; ++dt) m = fmaxf(m, acc[dt][r]);
      for (int sh = 1; sh < 16; sh <<= 1) m = fmaxf(m, __shfl_xor(m, sh));
      float s = 0.f;
      #pragma unroll
      for (int dt = 0; dt < 8; ++dt){ float e = __expf(acc[dt][r] - m); acc[dt][r] = e; s += e; }
      for (int sh = 1; sh < 16; sh <<= 1) s += __shfl_xor(s, sh);
      int row = c0 + (l >> 4)*4 + r;
      if ((l & 15) == 0){ Sf[oMRT + row] = m; Sf[oISRT + row] = 1.f / s; }
      #pragma unroll
      for (int dt = 0; dt < 8; ++dt) Up[row*136 + dt*16 + (l & 15)] = f2bf(acc[dt][r]);
    }
  }
  __syncthreads();

  // ---------- Ph5: E_s (waves 0-5, f16 MFMA) + Et col stats from bf16 U (waves 6-7) ----------
  if (wid < 6){
    int v0 = wid * 16;
    f32x4 acc[6] = {};
    for (int kk = 0; kk < 4; ++kk){
      f16x8 a = frag_ld(sm + THT + v0*136 + kk*32, 136);
      #pragma unroll
      for (int wt = 0; wt < 6; ++wt){
        f16x8 b = frag_ld(sm + PHT + wt*16*136 + kk*32, 136);
        acc[wt] = MFMA16(a, b, acc[wt]);
      }
    }
    #pragma unroll
    for (int r = 0; r < 4; ++r){
      float m = 0.f;   // pad cols are exactly 0 (phiT pad rows zeroed)
      #pragma unroll
      for (int wt = 0; wt < 6; ++wt) m = fmaxf(m, acc[wt][r]);
      for (int sh = 1; sh < 16; sh <<= 1) m = fmaxf(m, __shfl_xor(m, sh));
      float s = 0.f;
      #pragma unroll
      for (int wt = 0; wt < 6; ++wt){
        float e = __expf(acc[wt][r] - m);
        bool valid = (wt*16 + (l & 15)) < VV;
        acc[wt][r] = valid ? e : 0.f;
        s += acc[wt][r];
      }
      for (int sh = 1; sh < 16; sh <<= 1) s += __shfl_xor(s, sh);
      int row = v0 + (l >> 4)*4 + r;
      if ((l & 15) == 0){ Sf[oMRS + row] = m; Sf[oISRS + row] = 1.f / s; }
      if (row < VV){
        #pragma unroll
        for (int wt = 0; wt < 6; ++wt) USp[row*96 + wt*16 + (l & 15)] = f2bf(acc[wt][r]);
      }
    }
  } else {
    int c = tid - 384;  // 0..127: column stats of Et from U + mrt
    float m = -3e38f;
    for (int d = 0; d < 128; ++d){
      float u = bf2f(Up[d*136 + c]);
      float lv = Sf[oMRT + d] + ((u > 0.f) ? __logf(u) : -100.f);
      m = fmaxf(m, lv);
    }
    float s = 0.f;
    for (int d = 0; d < 128; ++d){
      float u = bf2f(Up[d*136 + c]);
      float lv = Sf[oMRT + d] + ((u > 0.f) ? __logf(u) : -100.f);
      s += __expf(lv - m);
    }
    Sf[oMCT + c] = m; Sf[oISCT + c] = 1.f / s;
  }
  __syncthreads();

  // ---------- Ph6: E_s col stats ----------
  if (tid < 96){
    int v = tid;
    float m = -3e38f;
    for (int w = 0; w < VV; ++w){
      float u = bf2f(USp[w*96 + v]);
      float lv = Sf[oMRS + w] + ((u > 0.f) ? __logf(u) : -100.f);
      m = fmaxf(m, lv);
    }
    float s = 0.f;
    for (int w = 0; w < VV; ++w){
      float u = bf2f(USp[w*96 + v]);
      float lv = Sf[oMRS + w] + ((u > 0.f) ? __logf(u) : -100.f);
      s += __expf(lv - m);
    }
    Sf[oMCS + v] = m; Sf[oISCS + v] = 1.f / s;
  }
  __syncthreads();

  // ---------- Ph7: M1 = AT2@g1 (folded), M2 = AT1@g2 (folded) — bf16 MFMA ----------
  {
    int c0 = wid * 16;
    const s16* G1 = (const s16*)(sm + G1T);
    const s16* G2 = (const s16*)(sm + G2T);
    s16* M1 = (s16*)(sm + M1o);
    s16* M2 = (s16*)(sm + M2o);
    // M1: AT2 numerators on-the-fly from U columns — log-space, overflow-proof:
    // exp(log u + MRT[d] - MCT[c]) = exp(E_t[d,c] - MCT[c]) <= 1
    {
      int ca = c0 + (l & 15);
      float mctc = Sf[oMCT + ca];
      f32x4 acc[6] = {};
      for (int kk = 0; kk < 4; ++kk){
        int db = kk*32 + (l >> 4) * 8;
        bf16x8 a;
        #pragma unroll
        for (int b = 0; b < 8; ++b){
          float u = bf2f(Up[(db + b)*136 + ca]);
          float val = (u > 0.f) ? __expf(__logf(u) + Sf[oMRT + db + b] - mctc) : 0.f;
          a[b] = f2bf(val);
        }
        #pragma unroll
        for (int vt = 0; vt < 6; ++vt){
          bf16x8 bfv = bfrag_ld(G1 + vt*16*136 + kk*32, 136);
          acc[vt] = MFMABF(a, bfv, acc[vt]);
        }
      }
      #pragma unroll
      for (int vt = 0; vt < 6; ++vt){
        int v = vt*16 + (l & 15);
        float cs = (v < VV) ? Sf[oISRS + v] : 0.f;
        #pragma unroll
        for (int r = 0; r < 4; ++r){
          int c = c0 + (l >> 4)*4 + r;
          M1[c*96 + v] = f2bf(acc[vt][r] * Sf[oISCT + c] * cs);
        }
      }
    }
    // M2: AT1 numerators contiguous from U rows
    {
      f32x4 acc[6] = {};
      for (int kk = 0; kk < 4; ++kk){
        bf16x8 a = bfrag_ld(Up + c0*136 + kk*32, 136);
        #pragma unroll
        for (int vt = 0; vt < 6; ++vt){
          bf16x8 bfv = bfrag_ld(G2 + vt*16*136 + kk*32, 136);
          acc[vt] = MFMABF(a, bfv, acc[vt]);
        }
      }
      #pragma unroll
      for (int vt = 0; vt < 6; ++vt){
        int v = vt*16 + (l & 15);
        float cs = (v < VV) ? Sf[oISCS + v] : 0.f;
        #pragma unroll
        for (int r = 0; r < 4; ++r){
          int c = c0 + (l >> 4)*4 + r;
          M2[c*96 + v] = f2bf(acc[vt][r] * Sf[oISRT + c] * cs);
        }
      }
    }
  }
  __syncthreads();

  // ---------- Ph8: z1T = AS2num^T @ M1^T ; z2T = AS1num^T @ M2^T — bf16 MFMA ----------
  for (int pass = 0; pass < 2; ++pass){
    int id = wid + pass*8;
    if (id >= 12) break;
    bool isZ2 = id >= 6;
    int w0 = (isZ2 ? id - 6 : id) * 16;
    int wa = w0 + (l & 15);
    const s16* Mx = (const s16*)(sm + (isZ2 ? M2o : M1o));
    s16* Z = (s16*)(sm + (isZ2 ? Z2o : Z1o));
    f32x4 acc[8] = {};
    for (int kk = 0; kk < 3; ++kk){
      int vb = kk*32 + (l >> 4) * 8;
      bf16x8 a;
      if (!isZ2){
        #pragma unroll
        for (int b = 0; b < 8; ++b){
          int v = vb + b;
          a[b] = (v < VV) ? USp[v*96 + wa] : (s16)0;
        }
      } else {
        // AS1 numerator: exp(log U[wa,v] + MRS[wa] - MCS[v]) = exp(E_s[wa,v]-MCS[v]) <= 1
        // log-space avoids the 0*inf NaN (pad cols) and exp overflow (tail).
        int wr = (wa < VV) ? wa : (VV - 1);
        const s16* up = USp + wr*96 + vb;
        float mrsw = Sf[oMRS + wr];
        #pragma unroll
        for (int b = 0; b < 8; ++b){
          float u = bf2f(up[b]);
          int v = vb + b;
          float val = (u > 0.f && v < VV && wa < VV)
                    ? __expf(__logf(u) + mrsw - Sf[oMCS + v]) : 0.f;
          a[b] = f2bf(val);
        }
      }
      #pragma unroll
      for (int ct = 0; ct < 8; ++ct){
        bf16x8 bfv = bfrag_ld(Mx + ct*16*96 + kk*32, 96);
        acc[ct] = MFMABF(a, bfv, acc[ct]);
      }
    }
    #pragma unroll
    for (int ct = 0; ct < 8; ++ct){
      #pragma unroll
      for (int r = 0; r < 4; ++r){
        int row = w0 + (l >> 4)*4 + r;
        Z[row*136 + ct*16 + (l & 15)] = f2bf(acc[ct][r]);
      }
    }
  }
  __syncthreads();

  // ---------- Ph9: z column sums, fusion weights ----------
  if (tid < 128){
    const s16* Z1 = (const s16*)(sm + Z1o);
    const s16* Z2 = (const s16*)(sm + Z2o);
    float s1 = 0.f, s2 = 0.f;
    for (int w = 0; w < VV; ++w){
      s1 += bf2f(Z1[w*136 + tid]);
      s2 += bf2f(Z2[w*136 + tid]);
    }
    float cw = csw[tid];
    Sf[oRED1 + tid] = cw * s1;
    Sf[oRED2 + tid] = cw * s2;
  }
  __syncthreads();
  if (tid == 0){
    float m1 = 0.f; for (int t = 0; t < 256; ++t) m1 += Sf[oX1MV + t]; m1 *= (1.f/256.f);
    float m2 = 0.f; for (int v = 0; v < VV; ++v) m2 += Sf[oX2MT + v]; m2 *= (1.f/90.f);
    float zd1 = 0.f, zd2 = 0.f;
    for (int c = 0; c < 128; ++c){ zd1 += Sf[oRED1 + c]; zd2 += Sf[oRED2 + c]; }
    float bws = bwsum[0];
    float mp1 = (zd1 + 90.f*bws) * (1.f/23040.f);
    float mp2 = (zd2 + 90.f*bws) * (1.f/23040.f);
    {
      float mx = fmaxf(m1, fmaxf(m2, mp1));
      float e0 = __expf(m1-mx), e1 = __expf(m2-mx), e2 = __expf(mp1-mx);
      float inv = 1.f/(e0+e1+e2);
      Sf[oSCAL+0] = e0*inv; Sf[oSCAL+1] = e1*inv; Sf[oSCAL+2] = e2*inv;
    }
    {
      float mx = fmaxf(m2, fmaxf(m1, mp2));
      float e0 = __expf(m2-mx), e1 = __expf(m1-mx), e2 = __expf(mp2-mx);
      float inv = 1.f/(e0+e1+e2);
      Sf[oSCAL+3] = e0*inv; Sf[oSCAL+4] = e1*inv; Sf[oSCAL+5] = e2*inv;
    }
  }
  __syncthreads();

  // ---------- Ph10: proj1/proj2 (bf16 MFMA) + fused outputs ----------
  {
    float w10 = Sf[oSCAL+0], w11 = Sf[oSCAL+1], w12 = Sf[oSCAL+2];
    float w20 = Sf[oSCAL+3], w21 = Sf[oSCAL+4], w22 = Sf[oSCAL+5];
    float* out1 = outg + (size_t)bid * BTV;
    float* out2 = outg + (size_t)NB * BTV + (size_t)bid * BTV;
    for (int pass = 0; pass < 4; ++pass){
      int sid = (pass >> 1)*8 + wid;
      bool is2 = pass & 1;
      int t0 = sid * 16;
      const s16* Zp = (const s16*)(sm + (is2 ? Z2o : Z1o));
      f32x4 acc[6] = {};
      for (int kk = 0; kk < 4; ++kk){
        bf16x8 a = bfrag_ld(WP + t0*128 + kk*32, 128);
        #pragma unroll
        for (int vt = 0; vt < 6; ++vt){
          bf16x8 b = bfrag_ld(Zp + vt*16*136 + kk*32, 136);
          acc[vt] = MFMABF(a, b, acc[vt]);
        }
      }
      const float* xb = is2 ? x2b : x1b;
      float* op = is2 ? out2 : out1;
      float wa = is2 ? w20 : w10, wb = is2 ? w21 : w11, wc = is2 ? w22 : w12;
      #pragma unroll
      for (int r = 0; r < 4; ++r){
        int t = t0 + (l >> 4)*4 + r;
        float bw = bwe[t];
        float crossv = is2 ? Sf[oX1MV + t] : 0.f;
        #pragma unroll
        for (int vt = 0; vt < 6; ++vt){
          int v = vt*16 + (l & 15);
          if (v < VV){
            float cross = is2 ? crossv : Sf[oX2MT + v];
            op[t*VV + v] = wa * xb[t*VV + v] + wb * cross + wc * (acc[vt][r] + bw);
          }
        }
      }
    }
  }
}

} // namespace

extern "C" void kernel_launch(void* const* d_in, const int* in_sizes, int n_in,
                              void* d_out, int out_size, void* d_ws, size_t ws_size,
                              hipStream_t stream)
{
  (void)in_sizes; (void)n_in; (void)out_size; (void)ws_size;
  hipFuncSetAttribute((const void*)stacif_main,
                      hipFuncAttributeMaxDynamicSharedMemorySize, SMEM_BYTES);

  const float* x1 = (const float*)d_in[0];
  const float* x2 = (const float*)d_in[1];
  const float* g_bng = (const float*)d_in[2];
  const float* g_bnb = (const float*)d_in[3];
  const float* g_bnm = (const float*)d_in[4];
  const float* g_bnv = (const float*)d_in[5];
  const float* g_w   = (const float*)d_in[6];
  const float* g_b   = (const float*)d_in[7];
  const float* th_bng = (const float*)d_in[8];
  const float* th_bnb = (const float*)d_in[9];
  const float* th_bnm = (const float*)d_in[10];
  const float* th_bnv = (const float*)d_in[11];
  const float* th_w   = (const float*)d_in[12];
  const float* th_b   = (const float*)d_in[13];
  const float* ph_bng = (const float*)d_in[14];
  const float* ph_bnb = (const float*)d_in[15];
  const float* ph_bnm = (const float*)d_in[16];
  const float* ph_bnv = (const float*)d_in[17];
  const float* ph_w   = (const float*)d_in[18];
  const float* ph_b   = (const float*)d_in[19];
  const float* W_w    = (const float*)d_in[20];
  const float* W_b    = (const float*)d_in[21];
  const float* W_bng  = (const float*)d_in[22];
  const float* W_bnb  = (const float*)d_in[23];
  const float* W_bnm  = (const float*)d_in[24];
  const float* W_bnv  = (const float*)d_in[25];
  char* ws = (char*)d_ws;
  float* out = (float*)d_out;

  prep_weights<<<dim3(256), dim3(256), 0, stream>>>(
      th_w, th_b, th_bng, th_bnb, th_bnm, th_bnv,
      g_w, g_b, g_bng, g_bnb, g_bnm, g_bnv,
      ph_w, ph_b, ph_bng, ph_bnb, ph_bnm, ph_bnv,
      W_w, W_b, W_bng, W_bnb, W_bnm, W_bnv, ws);
  prep_scalars<<<dim3(1), dim3(256), 0, stream>>>(W_w, W_bng, W_bnv, ws);
  stacif_main<<<dim3(NB), dim3(512), SMEM_BYTES, stream>>>(x1, x2, ws, out);
}

// Round 5
// 436.545 us; speedup vs baseline: 3.9971x; 1.2496x over previous
//
#include <hip/hip_runtime.h>

typedef unsigned int u32;
typedef _Float16 f16;
typedef short s16;
typedef _Float16 f16x8 __attribute__((ext_vector_type(8)));
typedef short bf16x8 __attribute__((ext_vector_type(8)));
typedef float f32x4 __attribute__((ext_vector_type(4)));

#define MFMA16(a,b,c) __builtin_amdgcn_mfma_f32_16x16x32_f16(a,b,c,0,0,0)
#define MFMABF(a,b,c) __builtin_amdgcn_mfma_f32_16x16x32_bf16(a,b,c,0,0,0)

namespace {

constexpr int VV = 90, BTV = 256*90, NB = 1024, NT = 1024;

// ---- LDS layout (2-byte-element offsets) ----
constexpr int XT  = 0;         // f16 [96][272] staging x1T / x2T
constexpr int UT  = 0;         // bf16 [128][136] exp(Et-rowmax); cols 128..135 = col-partial-max[wave]
constexpr int US  = 17408;     // bf16 [90][96]   exp(Es - rowmax)
constexpr int G1T = 26112;     // bf16 [96][136]
constexpr int THT = 39168;     // f16 [96][136]
constexpr int PHT = 52224;     // f16 [96][136]
constexpr int G2T = 65280;     // bf16 [96][136]  (ends 78336)
constexpr int M1o = 39168;     // bf16 [128][96]  over THT
constexpr int M2o = 51456;     // bf16 [128][96]
constexpr int Z1o = 26112;     // bf16 [96][136]  over G1T
constexpr int Z2o = 65280;     // bf16 [96][136]  over G2T
constexpr int SBASE = 78336;   // f32 stats area
constexpr int oX1MV=0, oX2MT=256, oMRT=352, oISRT=480, oMCT=608, oISCT=736,
              oMRS=864, oISRS=960, oMCS=1056, oISCS=1152, oRED1=1248, oRED2=1376, oSCAL=1504;
// oSCAL: 0..5 fusion weights, 8=M_s, 9=s1, 10=s2, 11=m1sum, 12=m2sum
constexpr int SWORDS = 1520;
constexpr int SMEM_BYTES = SBASE*2 + SWORDS*4;   // 162752 <= 163840

// ---- ws layout (bytes) ----
constexpr size_t wThP=0, wGP=65536, wPhP=131072, wWP=196608,
  wBeTh=262144, wBeG=262656, wBePh=263168, wBwe=263680, wCsw=264704, wBwsum=265216;

__device__ __forceinline__ f16x8 frag_ld(const f16* p, int stride){
  int l = threadIdx.x & 63;
  return *(const f16x8*)(p + (l & 15) * stride + (l >> 4) * 8);
}
__device__ __forceinline__ bf16x8 bfrag_ld(const s16* p, int stride){
  int l = threadIdx.x & 63;
  return *(const bf16x8*)(p + (l & 15) * stride + (l >> 4) * 8);
}
__device__ __forceinline__ s16 f2bf(float x){
  u32 u = __float_as_uint(x);
  u += 0x7FFFu + ((u >> 16) & 1u);   // RNE
  return (s16)(u >> 16);
}
__device__ __forceinline__ float bf2f(s16 h){
  return __uint_as_float(((u32)(unsigned short)h) << 16);
}

// =================== prep kernels (unchanged, correct) ===================
__global__ void prep_weights(
    const float* __restrict__ th_w, const float* __restrict__ th_b,
    const float* __restrict__ th_bng, const float* __restrict__ th_bnb,
    const float* __restrict__ th_bnm, const float* __restrict__ th_bnv,
    const float* __restrict__ g_w, const float* __restrict__ g_b,
    const float* __restrict__ g_bng, const float* __restrict__ g_bnb,
    const float* __restrict__ g_bnm, const float* __restrict__ g_bnv,
    const float* __restrict__ ph_w, const float* __restrict__ ph_b,
    const float* __restrict__ ph_bng, const float* __restrict__ ph_bnb,
    const float* __restrict__ ph_bnm, const float* __restrict__ ph_bnv,
    const float* __restrict__ W_w, const float* __restrict__ W_b,
    const float* __restrict__ W_bng, const float* __restrict__ W_bnb,
    const float* __restrict__ W_bnm, const float* __restrict__ W_bnv,
    char* __restrict__ ws)
{
  __shared__ float red[256];
  const int b = blockIdx.x, tid = threadIdx.x;
  f16* ThP = (f16*)(ws + wThP); f16* GP = (f16*)(ws + wGP);
  f16* PhP = (f16*)(ws + wPhP); s16* WP = (s16*)(ws + wWP);
  float* beTh = (float*)(ws + wBeTh); float* beG = (float*)(ws + wBeG);
  float* bePh = (float*)(ws + wBePh); float* bwe = (float*)(ws + wBwe);
  if (b < 128){
    const int c = b, t = tid;
    {
      float s = th_bng[t] * rsqrtf(th_bnv[t] + 1e-5f);
      float d = th_bnb[t] - th_bnm[t] * s;
      float w = th_w[c*256 + t];
      ThP[c*256 + t] = (f16)(w * s);
      red[tid] = w * d; __syncthreads();
      for (int o = 128; o > 0; o >>= 1){ if (tid < o) red[tid] += red[tid+o]; __syncthreads(); }
      if (tid == 0) beTh[c] = th_b[c] + red[0];
      __syncthreads();
    }
    {
      float s = g_bng[t] * rsqrtf(g_bnv[t] + 1e-5f);
      float d = g_bnb[t] - g_bnm[t] * s;
      float w = g_w[c*256 + t];
      GP[c*256 + t] = (f16)(w * s);
      red[tid] = w * d; __syncthreads();
      for (int o = 128; o > 0; o >>= 1){ if (tid < o) red[tid] += red[tid+o]; __syncthreads(); }
      if (tid == 0) beG[c] = g_b[c] + red[0];
      __syncthreads();
    }
    {
      float s = ph_bng[t] * rsqrtf(ph_bnv[t] + 1e-5f);
      float d = ph_bnb[t] - ph_bnm[t] * s;
      float w = ph_w[c*256 + t];
      PhP[c*256 + t] = (f16)(w * s);
      red[tid] = w * d; __syncthreads();
      for (int o = 128; o > 0; o >>= 1){ if (tid < o) red[tid] += red[tid+o]; __syncthreads(); }
      if (tid == 0) bePh[c] = ph_b[c] + red[0];
    }
  } else {
    const int t = (b - 128) * 2 + (tid >> 7);
    const int c = tid & 127;
    float s = W_bng[t] * rsqrtf(W_bnv[t] + 1e-5f);
    WP[t*128 + c] = f2bf(W_w[t*128 + c] * s);
    if (c == 0) bwe[t] = (W_b[t] - W_bnm[t]) * s + W_bnb[t];
  }
}

__global__ void prep_scalars(
    const float* __restrict__ W_w,
    const float* __restrict__ W_bng, const float* __restrict__ W_bnv,
    char* __restrict__ ws)
{
  const int tid = threadIdx.x;
  float* csw = (float*)(ws + wCsw); float* bwsum = (float*)(ws + wBwsum);
  const float* bwe = (const float*)(ws + wBwe);
  if (tid < 128){
    float a = 0.f;
    for (int t = 0; t < 256; ++t){
      float s = W_bng[t] * rsqrtf(W_bnv[t] + 1e-5f);
      a += W_w[t*128 + tid] * s;
    }
    csw[tid] = a;
  } else if (tid == 128){
    float a = 0.f;
    for (int t = 0; t < 256; ++t) a += bwe[t];
    bwsum[0] = a;
  }
}

// =================== main kernel: 1024 threads, 16 waves ===================
__global__ __launch_bounds__(NT, 1)
void stacif_main(const float* __restrict__ x1g, const float* __restrict__ x2g,
                 const char* __restrict__ ws, float* __restrict__ outg)
{
  extern __shared__ f16 sm[];
  float* Sf = (float*)(sm + SBASE);
  const int tid = threadIdx.x, bid = blockIdx.x;
  const int wid = tid >> 6, l = tid & 63;
  const float* __restrict__ x1b = x1g + (size_t)bid * BTV;
  const float* __restrict__ x2b = x2g + (size_t)bid * BTV;
  const f16* ThP = (const f16*)(ws + wThP);
  const f16* GP  = (const f16*)(ws + wGP);
  const f16* PhP = (const f16*)(ws + wPhP);
  const s16* WP  = (const s16*)(ws + wWP);
  const float* beTh = (const float*)(ws + wBeTh);
  const float* beG  = (const float*)(ws + wBeG);
  const float* bePh = (const float*)(ws + wBePh);
  const float* bwe  = (const float*)(ws + wBwe);
  const float* csw  = (const float*)(ws + wCsw);
  const float* bwsum = (const float*)(ws + wBwsum);
  s16* Up  = (s16*)(sm + UT);
  s16* USp = (s16*)(sm + US);

  // ---------- Ph0: stage x1^T ----------
  for (int i = tid; i < BTV; i += NT){
    int t = i / 90, v = i - t * 90;
    sm[XT + v*272 + t] = (f16)x1b[i];
  }
  __syncthreads();

  // ---------- Ph1: x1 row means + projections thetaT (f16), g1T (bf16), 48 units ----------
  {
    int t = tid >> 2, q = tid & 3;
    float a = 0.f;
    for (int v = q; v < VV; v += 4) a += (float)sm[XT + v*272 + t];
    a += __shfl_xor(a, 1); a += __shfl_xor(a, 2);
    if (q == 0) Sf[oX1MV + t] = a * (1.f/90.f);
  }
  for (int h = 0; h < 3; ++h){
    int u = wid*3 + h;
    int mat = u >= 24;
    int rem = mat ? u - 24 : u;
    int v0 = (rem >> 2) * 16, c0 = (rem & 3) * 32;
    const f16* Wm = mat ? GP : ThP;
    const float* beg = mat ? beG : beTh;
    f32x4 acc[2] = {};
    for (int kk = 0; kk < 8; ++kk){
      int k0 = kk * 32;
      f16x8 a = frag_ld(sm + XT + v0*272 + k0, 272);
      #pragma unroll
      for (int j = 0; j < 2; ++j){
        f16x8 b = frag_ld(Wm + (c0 + j*16)*256 + k0, 256);
        acc[j] = MFMA16(a, b, acc[j]);
      }
    }
    int vr = v0 + (l >> 4) * 4;
    #pragma unroll
    for (int j = 0; j < 2; ++j){
      int c = c0 + j*16 + (l & 15);
      float bias = beg[c];
      #pragma unroll
      for (int r = 0; r < 4; ++r){
        int v = vr + r;
        float val = acc[j][r] + bias;
        if (mat){
          ((s16*)(sm + G1T))[v*136 + c] = (v < VV) ? f2bf(val) : (s16)0;
        } else {
          sm[THT + v*136 + c] = (v < VV) ? (f16)val : (f16)0.0f;
        }
      }
    }
  }
  __syncthreads();

  // ---------- Ph2: stage x2^T ----------
  for (int i = tid; i < BTV; i += NT){
    int t = i / 90, v = i - t * 90;
    sm[XT + v*272 + t] = (f16)x2b[i];
  }
  __syncthreads();

  // ---------- Ph3: x2 col means + projections phiT (f16), g2T (bf16) ----------
  if (tid < 768){
    int v = tid >> 3, p = tid & 7;
    float a = 0.f;
    for (int j = 0; j < 32; ++j) a += (float)sm[XT + v*272 + p*32 + j];
    a += __shfl_xor(a, 1); a += __shfl_xor(a, 2); a += __shfl_xor(a, 4);
    if (p == 0 && v < VV) Sf[oX2MT + v] = a * (1.f/256.f);
  }
  for (int h = 0; h < 3; ++h){
    int u = wid*3 + h;
    int mat = u >= 24;
    int rem = mat ? u - 24 : u;
    int v0 = (rem >> 2) * 16, c0 = (rem & 3) * 32;
    const f16* Wm = mat ? GP : PhP;
    const float* beg = mat ? beG : bePh;
    f32x4 acc[2] = {};
    for (int kk = 0; kk < 8; ++kk){
      int k0 = kk * 32;
      f16x8 a = frag_ld(sm + XT + v0*272 + k0, 272);
      #pragma unroll
      for (int j = 0; j < 2; ++j){
        f16x8 b = frag_ld(Wm + (c0 + j*16)*256 + k0, 256);
        acc[j] = MFMA16(a, b, acc[j]);
      }
    }
    int vr = v0 + (l >> 4) * 4;
    #pragma unroll
    for (int j = 0; j < 2; ++j){
      int c = c0 + j*16 + (l & 15);
      float bias = beg[c];
      #pragma unroll
      for (int r = 0; r < 4; ++r){
        int v = vr + r;
        float val = acc[j][r] + bias;
        if (mat){
          ((s16*)(sm + G2T))[v*136 + c] = (v < VV) ? f2bf(val) : (s16)0;
        } else {
          sm[PHT + v*136 + c] = (v < VV) ? (f16)val : (f16)0.0f;
        }
      }
    }
  }
  __syncthreads();

  // ---------- Ph45: waves 0-7: E_t + row softmax + col-partial-max; waves 8-13: E_s ----------
  if (wid < 8){
    int c0 = wid * 16;
    int ca = c0 + (l & 15);
    f32x4 acc[8] = {};
    for (int kk = 0; kk < 3; ++kk){
      int vb = kk*32 + (l >> 4) * 8;
      f16x8 a;
      #pragma unroll
      for (int b = 0; b < 8; ++b) a[b] = sm[THT + (vb + b)*136 + ca];
      #pragma unroll
      for (int dt = 0; dt < 8; ++dt){
        int da = dt*16 + (l & 15);
        f16x8 bf;
        #pragma unroll
        for (int b = 0; b < 8; ++b) bf[b] = sm[PHT + (vb + b)*136 + da];
        acc[dt] = MFMA16(a, bf, acc[dt]);
      }
    }
    // column partial maxes (raw E, before exp) -> UT pad col 128+wid
    #pragma unroll
    for (int dt = 0; dt < 8; ++dt){
      float m4 = fmaxf(fmaxf(acc[dt][0], acc[dt][1]), fmaxf(acc[dt][2], acc[dt][3]));
      m4 = fmaxf(m4, __shfl_xor(m4, 16));
      m4 = fmaxf(m4, __shfl_xor(m4, 32));
      if (l < 16) Up[(dt*16 + l)*136 + 128 + wid] = f2bf(m4);
    }
    // row softmax
    #pragma unroll
    for (int r = 0; r < 4; ++r){
      float m = -3e38f;
      #pragma unroll
      for (int dt = 0; dt < 8; ++dt) m = fmaxf(m, acc[dt][r]);
      for (int sh = 1; sh < 16; sh <<= 1) m = fmaxf(m, __shfl_xor(m, sh));
      float s = 0.f;
      #pragma unroll
      for (int dt = 0; dt < 8; ++dt){ float e = __expf(acc[dt][r] - m); acc[dt][r] = e; s += e; }
      for (int sh = 1; sh < 16; sh <<= 1) s += __shfl_xor(s, sh);
      int row = c0 + (l >> 4)*4 + r;
      if ((l & 15) == 0){ Sf[oMRT + row] = m; Sf[oISRT + row] = 1.f / s; }
      #pragma unroll
      for (int dt = 0; dt < 8; ++dt) Up[row*136 + dt*16 + (l & 15)] = f2bf(acc[dt][r]);
    }
  } else if (wid < 14){
    int v0 = (wid - 8) * 16;
    f32x4 acc[6] = {};
    for (int kk = 0; kk < 4; ++kk){
      f16x8 a = frag_ld(sm + THT + v0*136 + kk*32, 136);
      #pragma unroll
      for (int wt = 0; wt < 6; ++wt){
        f16x8 b = frag_ld(sm + PHT + wt*16*136 + kk*32, 136);
        acc[wt] = MFMA16(a, b, acc[wt]);
      }
    }
    #pragma unroll
    for (int r = 0; r < 4; ++r){
      float m = 0.f;   // pad cols are exactly 0
      #pragma unroll
      for (int wt = 0; wt < 6; ++wt) m = fmaxf(m, acc[wt][r]);
      for (int sh = 1; sh < 16; sh <<= 1) m = fmaxf(m, __shfl_xor(m, sh));
      float s = 0.f;
      #pragma unroll
      for (int wt = 0; wt < 6; ++wt){
        float e = __expf(acc[wt][r] - m);
        bool valid = (wt*16 + (l & 15)) < VV;
        acc[wt][r] = valid ? e : 0.f;
        s += acc[wt][r];
      }
      for (int sh = 1; sh < 16; sh <<= 1) s += __shfl_xor(s, sh);
      int row = v0 + (l >> 4)*4 + r;
      if ((l & 15) == 0){ Sf[oMRS + row] = m; Sf[oISRS + row] = 1.f / s; }
      if (row < VV){
        #pragma unroll
        for (int wt = 0; wt < 6; ++wt) USp[row*96 + wt*16 + (l & 15)] = f2bf(acc[wt][r]);
      }
    }
  }
  __syncthreads();

  // ---------- Ph5b: Et col stats (no logs), wave15 also reduces M_s ----------
  {
    int c = tid >> 3, p = tid & 7;
    float mp = bf2f(Up[c*136 + 128 + p]);
    mp = fmaxf(mp, __shfl_xor(mp, 1));
    mp = fmaxf(mp, __shfl_xor(mp, 2));
    mp = fmaxf(mp, __shfl_xor(mp, 4));
    float s = 0.f;
    #pragma unroll
    for (int j = 0; j < 16; ++j){
      int d = p*16 + j;
      float u = bf2f(Up[d*136 + c]);
      if (u > 0.f){
        float e1 = __expf(0.5f * (Sf[oMRT + d] - mp));
        s += (u * e1) * e1;
      }
    }
    s += __shfl_xor(s, 1); s += __shfl_xor(s, 2); s += __shfl_xor(s, 4);
    if (p == 0){ Sf[oMCT + c] = mp; Sf[oISCT + c] = 1.f / s; }
  }
  if (wid == 15){
    float m = (l < 96) ? Sf[oMRS + l] : -3e38f;
    if (l < 32) m = fmaxf(m, Sf[oMRS + 64 + l]);
    for (int sh = 1; sh < 64; sh <<= 1) m = fmaxf(m, __shfl_xor(m, sh));
    if (l == 0) Sf[oSCAL + 8] = m;
  }
  __syncthreads();

  // ---------- Ph6: Es col sums with global-max trick ----------
  if (tid < 768){
    int v = tid >> 3, p = tid & 7;
    float Ms = Sf[oSCAL + 8];
    float s = 0.f;
    for (int j = 0; j < 12; ++j){
      int w = p*12 + j;
      if (w < VV){
        float u = bf2f(USp[w*96 + v]);
        if (u > 0.f) s += u * __expf(Sf[oMRS + w] - Ms);
      }
    }
    s += __shfl_xor(s, 1); s += __shfl_xor(s, 2); s += __shfl_xor(s, 4);
    if (p == 0) Sf[oISCS + v] = 1.f / fmaxf(s, 1e-30f);
  }
  __syncthreads();

  // ---------- Ph7: M1 (waves 0-7), M2 (waves 8-15) — bf16 MFMA ----------
  if (wid < 8){
    int c0 = wid * 16;
    const s16* G1 = (const s16*)(sm + G1T);
    s16* M1 = (s16*)(sm + M1o);
    int ca = c0 + (l & 15);
    float mctc = Sf[oMCT + ca];
    f32x4 acc[6] = {};
    for (int kk = 0; kk < 4; ++kk){
      int db = kk*32 + (l >> 4) * 8;
      bf16x8 a;
      #pragma unroll
      for (int b = 0; b < 8; ++b){
        float u = bf2f(Up[(db + b)*136 + ca]);
        float val = 0.f;
        if (u > 0.f){
          float e1 = __expf(0.5f * (Sf[oMRT + db + b] - mctc));
          val = (u * e1) * e1;      // = exp(Et[d,c]-mct[c]) <= ~1
        }
        a[b] = f2bf(val);
      }
      #pragma unroll
      for (int vt = 0; vt < 6; ++vt){
        bf16x8 bfv = bfrag_ld(G1 + vt*16*136 + kk*32, 136);
        acc[vt] = MFMABF(a, bfv, acc[vt]);
      }
    }
    #pragma unroll
    for (int vt = 0; vt < 6; ++vt){
      int v = vt*16 + (l & 15);
      float cs = (v < VV) ? Sf[oISRS + v] : 0.f;
      #pragma unroll
      for (int r = 0; r < 4; ++r){
        int c = c0 + (l >> 4)*4 + r;
        M1[c*96 + v] = f2bf(acc[vt][r] * Sf[oISCT + c] * cs);
      }
    }
  } else {
    int c0 = (wid - 8) * 16;
    const s16* G2 = (const s16*)(sm + G2T);
    s16* M2 = (s16*)(sm + M2o);
    f32x4 acc[6] = {};
    for (int kk = 0; kk < 4; ++kk){
      bf16x8 a = bfrag_ld(Up + c0*136 + kk*32, 136);
      #pragma unroll
      for (int vt = 0; vt < 6; ++vt){
        bf16x8 bfv = bfrag_ld(G2 + vt*16*136 + kk*32, 136);
        acc[vt] = MFMABF(a, bfv, acc[vt]);
      }
    }
    #pragma unroll
    for (int vt = 0; vt < 6; ++vt){
      int v = vt*16 + (l & 15);
      float cs = (v < VV) ? Sf[oISCS + v] : 0.f;
      #pragma unroll
      for (int r = 0; r < 4; ++r){
        int c = c0 + (l >> 4)*4 + r;
        M2[c*96 + v] = f2bf(acc[vt][r] * Sf[oISRT + c] * cs);
      }
    }
  }
  __syncthreads();

  // ---------- Ph8: z1T / z2T — 24 units (w-tile x ct-half x z), 2 passes ----------
  for (int pass = 0; pass < 2; ++pass){
    int u = wid + pass*16;
    if (u >= 24) break;
    bool isZ2 = u >= 12;
    int rem = isZ2 ? u - 12 : u;
    int w0 = (rem >> 1) * 16;
    int cth = rem & 1;             // ct in [cth*4, cth*4+4)
    int wa = w0 + (l & 15);
    const s16* Mx = (const s16*)(sm + (isZ2 ? M2o : M1o));
    s16* Z = (s16*)(sm + (isZ2 ? Z2o : Z1o));
    float e_row = 0.f;
    int wr = (wa < VV) ? wa : (VV - 1);
    if (isZ2) e_row = __expf(Sf[oMRS + wr] - Sf[oSCAL + 8]);   // <= 1
    f32x4 acc[4] = {};
    for (int kk = 0; kk < 3; ++kk){
      int vb = kk*32 + (l >> 4) * 8;
      bf16x8 a;
      if (!isZ2){
        #pragma unroll
        for (int b = 0; b < 8; ++b){
          int v = vb + b;
          a[b] = (v < VV) ? USp[v*96 + wa] : (s16)0;
        }
      } else {
        const s16* up = USp + wr*96 + vb;
        #pragma unroll
        for (int b = 0; b < 8; ++b){
          a[b] = f2bf(bf2f(up[b]) * e_row);   // exp(Es[wa,v]-Ms), pad cols u=0 -> 0
        }
      }
      #pragma unroll
      for (int ct = 0; ct < 4; ++ct){
        bf16x8 bfv = bfrag_ld(Mx + (cth*4 + ct)*16*96 + kk*32, 96);
        acc[ct] = MFMABF(a, bfv, acc[ct]);
      }
    }
    #pragma unroll
    for (int ct = 0; ct < 4; ++ct){
      #pragma unroll
      for (int r = 0; r < 4; ++r){
        int row = w0 + (l >> 4)*4 + r;
        Z[row*136 + (cth*4 + ct)*16 + (l & 15)] = f2bf(acc[ct][r]);
      }
    }
  }
  __syncthreads();

  // ---------- Ph9a: z column sums (1024 threads) ----------
  {
    int col = tid >> 3, zi = (tid >> 2) & 1, p = tid & 3;
    const s16* Z = (const s16*)(sm + (zi ? Z2o : Z1o));
    float s = 0.f;
    for (int j = 0; j < 23; ++j){
      int w = p*23 + j;
      if (w < VV) s += bf2f(Z[w*136 + col]);
    }
    s += __shfl_xor(s, 1); s += __shfl_xor(s, 2);
    if (p == 0){
      float* R = Sf + (zi ? oRED2 : oRED1);
      R[col] = csw[col] * s;
    }
  }
  __syncthreads();
  // ---------- Ph9b: final reductions by 4 waves, then tid0 ----------
  if (wid == 0){
    float s = Sf[oRED1 + l] + Sf[oRED1 + 64 + l];
    for (int sh = 1; sh < 64; sh <<= 1) s += __shfl_xor(s, sh);
    if (l == 0) Sf[oSCAL + 9] = s;
  } else if (wid == 1){
    float s = Sf[oRED2 + l] + Sf[oRED2 + 64 + l];
    for (int sh = 1; sh < 64; sh <<= 1) s += __shfl_xor(s, sh);
    if (l == 0) Sf[oSCAL + 10] = s;
  } else if (wid == 2){
    float s = 0.f;
    #pragma unroll
    for (int j = 0; j < 4; ++j) s += Sf[oX1MV + l*4 + j];
    for (int sh = 1; sh < 64; sh <<= 1) s += __shfl_xor(s, sh);
    if (l == 0) Sf[oSCAL + 11] = s;
  } else if (wid == 3){
    float s = Sf[oX2MT + l] * 0.f;
    s = (l < VV) ? Sf[oX2MT + l] : 0.f;
    if (l < 26) s += Sf[oX2MT + 64 + l];
    for (int sh = 1; sh < 64; sh <<= 1) s += __shfl_xor(s, sh);
    if (l == 0) Sf[oSCAL + 12] = s;
  }
  __syncthreads();
  if (tid == 0){
    float m1 = Sf[oSCAL + 11] * (1.f/256.f);
    float m2 = Sf[oSCAL + 12] * (1.f/90.f);
    float zd1 = Sf[oSCAL + 9], zd2 = Sf[oSCAL + 10];
    float bws = bwsum[0];
    float mp1 = (zd1 + 90.f*bws) * (1.f/23040.f);
    float mp2 = (zd2 + 90.f*bws) * (1.f/23040.f);
    {
      float mx = fmaxf(m1, fmaxf(m2, mp1));
      float e0 = __expf(m1-mx), e1 = __expf(m2-mx), e2 = __expf(mp1-mx);
      float inv = 1.f/(e0+e1+e2);
      Sf[oSCAL+0] = e0*inv; Sf[oSCAL+1] = e1*inv; Sf[oSCAL+2] = e2*inv;
    }
    {
      float mx = fmaxf(m2, fmaxf(m1, mp2));
      float e0 = __expf(m2-mx), e1 = __expf(m1-mx), e2 = __expf(mp2-mx);
      float inv = 1.f/(e0+e1+e2);
      Sf[oSCAL+3] = e0*inv; Sf[oSCAL+4] = e1*inv; Sf[oSCAL+5] = e2*inv;
    }
  }
  __syncthreads();

  // ---------- Ph10: proj + fused outputs — 32 units over 16 waves, 2 passes ----------
  {
    float* out1 = outg + (size_t)bid * BTV;
    float* out2 = outg + (size_t)NB * BTV + (size_t)bid * BTV;
    for (int pass = 0; pass < 2; ++pass){
      int u = wid + pass*16;
      bool is2 = u & 1;
      int t0 = (u >> 1) * 16;
      const s16* Zp = (const s16*)(sm + (is2 ? Z2o : Z1o));
      f32x4 acc[6] = {};
      for (int kk = 0; kk < 4; ++kk){
        bf16x8 a = bfrag_ld(WP + t0*128 + kk*32, 128);
        #pragma unroll
        for (int vt = 0; vt < 6; ++vt){
          bf16x8 b = bfrag_ld(Zp + vt*16*136 + kk*32, 136);
          acc[vt] = MFMABF(a, b, acc[vt]);
        }
      }
      const float* xb = is2 ? x2b : x1b;
      float* op = is2 ? out2 : out1;
      float wa = is2 ? Sf[oSCAL+3] : Sf[oSCAL+0];
      float wb = is2 ? Sf[oSCAL+4] : Sf[oSCAL+1];
      float wc = is2 ? Sf[oSCAL+5] : Sf[oSCAL+2];
      #pragma unroll
      for (int r = 0; r < 4; ++r){
        int t = t0 + (l >> 4)*4 + r;
        float bw = bwe[t];
        float crossv = is2 ? Sf[oX1MV + t] : 0.f;
        #pragma unroll
        for (int vt = 0; vt < 6; ++vt){
          int v = vt*16 + (l & 15);
          if (v < VV){
            float cross = is2 ? crossv : Sf[oX2MT + v];
            op[t*VV + v] = wa * xb[t*VV + v] + wb * cross + wc * (acc[vt][r] + bw);
          }
        }
      }
    }
  }
}

} // namespace

extern "C" void kernel_launch(void* const* d_in, const int* in_sizes, int n_in,
                              void* d_out, int out_size, void* d_ws, size_t ws_size,
                              hipStream_t stream)
{
  (void)in_sizes; (void)n_in; (void)out_size; (void)ws_size;
  hipFuncSetAttribute((const void*)stacif_main,
                      hipFuncAttributeMaxDynamicSharedMemorySize, SMEM_BYTES);

  const float* x1 = (const float*)d_in[0];
  const float* x2 = (const float*)d_in[1];
  const float* g_bng = (const float*)d_in[2];
  const float* g_bnb = (const float*)d_in[3];
  const float* g_bnm = (const float*)d_in[4];
  const float* g_bnv = (const float*)d_in[5];
  const float* g_w   = (const float*)d_in[6];
  const float* g_b   = (const float*)d_in[7];
  const float* th_bng = (const float*)d_in[8];
  const float* th_bnb = (const float*)d_in[9];
  const float* th_bnm = (const float*)d_in[10];
  const float* th_bnv = (const float*)d_in[11];
  const float* th_w   = (const float*)d_in[12];
  const float* th_b   = (const float*)d_in[13];
  const float* ph_bng = (const float*)d_in[14];
  const float* ph_bnb = (const float*)d_in[15];
  const float* ph_bnm = (const float*)d_in[16];
  const float* ph_bnv = (const float*)d_in[17];
  const float* ph_w   = (const float*)d_in[18];
  const float* ph_b   = (const float*)d_in[19];
  const float* W_w    = (const float*)d_in[20];
  const float* W_b    = (const float*)d_in[21];
  const float* W_bng  = (const float*)d_in[22];
  const float* W_bnb  = (const float*)d_in[23];
  const float* W_bnm  = (const float*)d_in[24];
  const float* W_bnv  = (const float*)d_in[25];
  char* ws = (char*)d_ws;
  float* out = (float*)d_out;

  prep_weights<<<dim3(256), dim3(256), 0, stream>>>(
      th_w, th_b, th_bng, th_bnb, th_bnm, th_bnv,
      g_w, g_b, g_bng, g_bnb, g_bnm, g_bnv,
      ph_w, ph_b, ph_bng, ph_bnb, ph_bnm, ph_bnv,
      W_w, W_b, W_bng, W_bnb, W_bnm, W_bnv, ws);
  prep_scalars<<<dim3(1), dim3(256), 0, stream>>>(W_w, W_bng, W_bnv, ws);
  stacif_main<<<dim3(NB), dim3(NT), SMEM_BYTES, stream>>>(x1, x2, ws, out);
}

// Round 6
// 305.143 us; speedup vs baseline: 5.7184x; 1.4306x over previous
//
#include <hip/hip_runtime.h>

typedef unsigned int u32;
typedef _Float16 f16;
typedef short s16;
typedef _Float16 f16x8 __attribute__((ext_vector_type(8)));
typedef short bf16x8 __attribute__((ext_vector_type(8)));
typedef float f32x4 __attribute__((ext_vector_type(4)));

#define MFMA16(a,b,c) __builtin_amdgcn_mfma_f32_16x16x32_f16(a,b,c,0,0,0)
#define MFMABF(a,b,c) __builtin_amdgcn_mfma_f32_16x16x32_bf16(a,b,c,0,0,0)

namespace {

constexpr int VV = 90, BTV = 256*90, NB = 1024, NT = 1024;

// ---- LDS layout (2-byte-element offsets) ----
constexpr int XT  = 0;         // f16 [96][272] staging x1T / x2T
constexpr int UT  = 0;         // bf16 [128][136]; cols 128..135 = col-partial-max[wave]
constexpr int US  = 17408;     // bf16 [90][96]
constexpr int G1T = 26112;     // bf16 [96][136]
constexpr int THT = 39168;     // f16 [96][136]
constexpr int PHT = 52224;     // f16 [96][136]
constexpr int G2T = 65280;     // bf16 [96][136]  (ends 78336)
constexpr int M1o = 39168;     // bf16 [128][96]  over THT
constexpr int M2o = 51456;     // bf16 [128][96]
constexpr int Z1o = 26112;     // bf16 [96][136]  over G1T
constexpr int Z2o = 65280;     // bf16 [96][136]  over G2T
constexpr int SBASE = 78336;   // f32 stats area
constexpr int oX1MV=0, oX2MT=256, oMRT=352, oISRT=480, oMCT=608, oISCT=736,
              oMRS=864, oISRS=960, oMCS=1056, oISCS=1152, oRED1=1248, oRED2=1376, oSCAL=1504;
// oSCAL: 0..5 fusion weights, 8=M_s, 9=s1, 10=s2, 11=m1sum, 12=m2sum
constexpr int SWORDS = 1520;
constexpr int SMEM_BYTES = SBASE*2 + SWORDS*4;   // 162752 <= 163840

// ---- ws layout (bytes) ----
constexpr size_t wThP=0, wGP=65536, wPhP=131072, wWP=196608,
  wBeTh=262144, wBeG=262656, wBePh=263168, wBwe=263680, wCsw=264704, wBwsum=265216;

__device__ __forceinline__ f16x8 frag_ld(const f16* p, int stride){
  int l = threadIdx.x & 63;
  return *(const f16x8*)(p + (l & 15) * stride + (l >> 4) * 8);
}
__device__ __forceinline__ bf16x8 bfrag_ld(const s16* p, int stride){
  int l = threadIdx.x & 63;
  return *(const bf16x8*)(p + (l & 15) * stride + (l >> 4) * 8);
}
__device__ __forceinline__ s16 f2bf(float x){
  u32 u = __float_as_uint(x);
  u += 0x7FFFu + ((u >> 16) & 1u);   // RNE
  return (s16)(u >> 16);
}
__device__ __forceinline__ float bf2f(s16 h){
  return __uint_as_float(((u32)(unsigned short)h) << 16);
}

// =================== prep kernels (unchanged, correct) ===================
__global__ void prep_weights(
    const float* __restrict__ th_w, const float* __restrict__ th_b,
    const float* __restrict__ th_bng, const float* __restrict__ th_bnb,
    const float* __restrict__ th_bnm, const float* __restrict__ th_bnv,
    const float* __restrict__ g_w, const float* __restrict__ g_b,
    const float* __restrict__ g_bng, const float* __restrict__ g_bnb,
    const float* __restrict__ g_bnm, const float* __restrict__ g_bnv,
    const float* __restrict__ ph_w, const float* __restrict__ ph_b,
    const float* __restrict__ ph_bng, const float* __restrict__ ph_bnb,
    const float* __restrict__ ph_bnm, const float* __restrict__ ph_bnv,
    const float* __restrict__ W_w, const float* __restrict__ W_b,
    const float* __restrict__ W_bng, const float* __restrict__ W_bnb,
    const float* __restrict__ W_bnm, const float* __restrict__ W_bnv,
    char* __restrict__ ws)
{
  __shared__ float red[256];
  const int b = blockIdx.x, tid = threadIdx.x;
  f16* ThP = (f16*)(ws + wThP); f16* GP = (f16*)(ws + wGP);
  f16* PhP = (f16*)(ws + wPhP); s16* WP = (s16*)(ws + wWP);
  float* beTh = (float*)(ws + wBeTh); float* beG = (float*)(ws + wBeG);
  float* bePh = (float*)(ws + wBePh); float* bwe = (float*)(ws + wBwe);
  if (b < 128){
    const int c = b, t = tid;
    {
      float s = th_bng[t] * rsqrtf(th_bnv[t] + 1e-5f);
      float d = th_bnb[t] - th_bnm[t] * s;
      float w = th_w[c*256 + t];
      ThP[c*256 + t] = (f16)(w * s);
      red[tid] = w * d; __syncthreads();
      for (int o = 128; o > 0; o >>= 1){ if (tid < o) red[tid] += red[tid+o]; __syncthreads(); }
      if (tid == 0) beTh[c] = th_b[c] + red[0];
      __syncthreads();
    }
    {
      float s = g_bng[t] * rsqrtf(g_bnv[t] + 1e-5f);
      float d = g_bnb[t] - g_bnm[t] * s;
      float w = g_w[c*256 + t];
      GP[c*256 + t] = (f16)(w * s);
      red[tid] = w * d; __syncthreads();
      for (int o = 128; o > 0; o >>= 1){ if (tid < o) red[tid] += red[tid+o]; __syncthreads(); }
      if (tid == 0) beG[c] = g_b[c] + red[0];
      __syncthreads();
    }
    {
      float s = ph_bng[t] * rsqrtf(ph_bnv[t] + 1e-5f);
      float d = ph_bnb[t] - ph_bnm[t] * s;
      float w = ph_w[c*256 + t];
      PhP[c*256 + t] = (f16)(w * s);
      red[tid] = w * d; __syncthreads();
      for (int o = 128; o > 0; o >>= 1){ if (tid < o) red[tid] += red[tid+o]; __syncthreads(); }
      if (tid == 0) bePh[c] = ph_b[c] + red[0];
    }
  } else {
    const int t = (b - 128) * 2 + (tid >> 7);
    const int c = tid & 127;
    float s = W_bng[t] * rsqrtf(W_bnv[t] + 1e-5f);
    WP[t*128 + c] = f2bf(W_w[t*128 + c] * s);
    if (c == 0) bwe[t] = (W_b[t] - W_bnm[t]) * s + W_bnb[t];
  }
}

__global__ void prep_scalars(
    const float* __restrict__ W_w,
    const float* __restrict__ W_bng, const float* __restrict__ W_bnv,
    char* __restrict__ ws)
{
  const int tid = threadIdx.x;
  float* csw = (float*)(ws + wCsw); float* bwsum = (float*)(ws + wBwsum);
  const float* bwe = (const float*)(ws + wBwe);
  if (tid < 128){
    float a = 0.f;
    for (int t = 0; t < 256; ++t){
      float s = W_bng[t] * rsqrtf(W_bnv[t] + 1e-5f);
      a += W_w[t*128 + tid] * s;
    }
    csw[tid] = a;
  } else if (tid == 128){
    float a = 0.f;
    for (int t = 0; t < 256; ++t) a += bwe[t];
    bwsum[0] = a;
  }
}

// =================== main kernel: 1024 threads, 16 waves ===================
__global__ __launch_bounds__(NT, 1)
void stacif_main(const float* __restrict__ x1g, const float* __restrict__ x2g,
                 const char* __restrict__ ws, float* __restrict__ outg)
{
  extern __shared__ f16 sm[];
  float* Sf = (float*)(sm + SBASE);
  const int tid = threadIdx.x, bid = blockIdx.x;
  const int wid = tid >> 6, l = tid & 63;
  const float* __restrict__ x1b = x1g + (size_t)bid * BTV;
  const float* __restrict__ x2b = x2g + (size_t)bid * BTV;
  const f16* ThP = (const f16*)(ws + wThP);
  const f16* GP  = (const f16*)(ws + wGP);
  const f16* PhP = (const f16*)(ws + wPhP);
  const s16* WP  = (const s16*)(ws + wWP);
  const float* beTh = (const float*)(ws + wBeTh);
  const float* beG  = (const float*)(ws + wBeG);
  const float* bePh = (const float*)(ws + wBePh);
  const float* bwe  = (const float*)(ws + wBwe);
  const float* csw  = (const float*)(ws + wCsw);
  const float* bwsum = (const float*)(ws + wBwsum);
  s16* Up  = (s16*)(sm + UT);
  s16* USp = (s16*)(sm + US);

  // per-thread staging coords: thread (tS, qS) owns row tS, v in [qS*23, qS*23+23)
  const int tS = tid >> 2, qS = tid & 3, vB = qS * 23;

  // ---------- Ph0: prefetch x1+x2 to regs; x1 row-mean; stage x1^T ----------
  float r1[23], r2[23];
  {
    const float* p1 = x1b + tS * 90;
    const float* p2 = x2b + tS * 90;
    #pragma unroll
    for (int j = 0; j < 23; ++j){
      int off = vB + j; off = (off < 90) ? off : 89;
      r1[j] = p1[off];
    }
    #pragma unroll
    for (int j = 0; j < 23; ++j){
      int off = vB + j; off = (off < 90) ? off : 89;
      r2[j] = p2[off];
    }
    float a = 0.f;
    #pragma unroll
    for (int j = 0; j < 23; ++j) if (vB + j < 90) a += r1[j];
    a += __shfl_xor(a, 1); a += __shfl_xor(a, 2);
    if (qS == 0) Sf[oX1MV + tS] = a * (1.f/90.f);
    #pragma unroll
    for (int j = 0; j < 23; ++j){
      int v = vB + j;
      if (v < 90) sm[XT + v*272 + tS] = (f16)r1[j];
    }
  }
  __syncthreads();

  // ---------- Ph1: proj thetaT (waves 0-7) / g1T (waves 8-15): 1 c-tile/wave ----------
  {
    const int mat = wid >> 3;
    const int c0 = (wid & 7) * 16;
    const f16* Wm = mat ? GP : ThP;
    const float* beg = mat ? beG : beTh;
    f32x4 acc[6] = {};
    for (int kk = 0; kk < 8; ++kk){
      f16x8 b = frag_ld(Wm + c0*256 + kk*32, 256);   // one global B-frag, reused 6x
      #pragma unroll
      for (int vt = 0; vt < 6; ++vt){
        f16x8 a = frag_ld(sm + XT + vt*16*272 + kk*32, 272);
        acc[vt] = MFMA16(a, b, acc[vt]);
      }
    }
    int c = c0 + (l & 15);
    float bias = beg[c];
    #pragma unroll
    for (int vt = 0; vt < 6; ++vt){
      #pragma unroll
      for (int r = 0; r < 4; ++r){
        int v = vt*16 + (l >> 4)*4 + r;
        float val = acc[vt][r] + bias;
        if (mat) ((s16*)(sm + G1T))[v*136 + c] = (v < VV) ? f2bf(val) : (s16)0;
        else     sm[THT + v*136 + c] = (v < VV) ? (f16)val : (f16)0.0f;
      }
    }
  }
  __syncthreads();

  // ---------- Ph2: stage x2^T from regs (loads long in flight) ----------
  #pragma unroll
  for (int j = 0; j < 23; ++j){
    int v = vB + j;
    if (v < 90) sm[XT + v*272 + tS] = (f16)r2[j];
  }
  __syncthreads();

  // ---------- Ph3: x2 col means + proj phiT / g2T ----------
  if (tid < 768){
    int v = tid >> 3, p = tid & 7;
    float a = 0.f;
    for (int j = 0; j < 32; ++j) a += (float)sm[XT + v*272 + p*32 + j];
    a += __shfl_xor(a, 1); a += __shfl_xor(a, 2); a += __shfl_xor(a, 4);
    if (p == 0 && v < VV) Sf[oX2MT + v] = a * (1.f/256.f);
  }
  {
    const int mat = wid >> 3;
    const int c0 = (wid & 7) * 16;
    const f16* Wm = mat ? GP : PhP;
    const float* beg = mat ? beG : bePh;
    f32x4 acc[6] = {};
    for (int kk = 0; kk < 8; ++kk){
      f16x8 b = frag_ld(Wm + c0*256 + kk*32, 256);
      #pragma unroll
      for (int vt = 0; vt < 6; ++vt){
        f16x8 a = frag_ld(sm + XT + vt*16*272 + kk*32, 272);
        acc[vt] = MFMA16(a, b, acc[vt]);
      }
    }
    int c = c0 + (l & 15);
    float bias = beg[c];
    #pragma unroll
    for (int vt = 0; vt < 6; ++vt){
      #pragma unroll
      for (int r = 0; r < 4; ++r){
        int v = vt*16 + (l >> 4)*4 + r;
        float val = acc[vt][r] + bias;
        if (mat) ((s16*)(sm + G2T))[v*136 + c] = (v < VV) ? f2bf(val) : (s16)0;
        else     sm[PHT + v*136 + c] = (v < VV) ? (f16)val : (f16)0.0f;
      }
    }
  }
  __syncthreads();

  // ---------- Ph45: waves 0-7: E_t + row softmax + col-partial-max; waves 8-13: E_s ----------
  if (wid < 8){
    int c0 = wid * 16;
    int ca = c0 + (l & 15);
    f32x4 acc[8] = {};
    for (int kk = 0; kk < 3; ++kk){
      int vb = kk*32 + (l >> 4) * 8;
      f16x8 a;
      #pragma unroll
      for (int b = 0; b < 8; ++b) a[b] = sm[THT + (vb + b)*136 + ca];
      #pragma unroll
      for (int dt = 0; dt < 8; ++dt){
        int da = dt*16 + (l & 15);
        f16x8 bf;
        #pragma unroll
        for (int b = 0; b < 8; ++b) bf[b] = sm[PHT + (vb + b)*136 + da];
        acc[dt] = MFMA16(a, bf, acc[dt]);
      }
    }
    #pragma unroll
    for (int dt = 0; dt < 8; ++dt){
      float m4 = fmaxf(fmaxf(acc[dt][0], acc[dt][1]), fmaxf(acc[dt][2], acc[dt][3]));
      m4 = fmaxf(m4, __shfl_xor(m4, 16));
      m4 = fmaxf(m4, __shfl_xor(m4, 32));
      if (l < 16) Up[(dt*16 + l)*136 + 128 + wid] = f2bf(m4);
    }
    #pragma unroll
    for (int r = 0; r < 4; ++r){
      float m = -3e38f;
      #pragma unroll
      for (int dt = 0; dt < 8; ++dt) m = fmaxf(m, acc[dt][r]);
      for (int sh = 1; sh < 16; sh <<= 1) m = fmaxf(m, __shfl_xor(m, sh));
      float s = 0.f;
      #pragma unroll
      for (int dt = 0; dt < 8; ++dt){ float e = __expf(acc[dt][r] - m); acc[dt][r] = e; s += e; }
      for (int sh = 1; sh < 16; sh <<= 1) s += __shfl_xor(s, sh);
      int row = c0 + (l >> 4)*4 + r;
      if ((l & 15) == 0){ Sf[oMRT + row] = m; Sf[oISRT + row] = 1.f / s; }
      #pragma unroll
      for (int dt = 0; dt < 8; ++dt) Up[row*136 + dt*16 + (l & 15)] = f2bf(acc[dt][r]);
    }
  } else if (wid < 14){
    int v0 = (wid - 8) * 16;
    f32x4 acc[6] = {};
    for (int kk = 0; kk < 4; ++kk){
      f16x8 a = frag_ld(sm + THT + v0*136 + kk*32, 136);
      #pragma unroll
      for (int wt = 0; wt < 6; ++wt){
        f16x8 b = frag_ld(sm + PHT + wt*16*136 + kk*32, 136);
        acc[wt] = MFMA16(a, b, acc[wt]);
      }
    }
    #pragma unroll
    for (int r = 0; r < 4; ++r){
      float m = 0.f;   // pad cols are exactly 0
      #pragma unroll
      for (int wt = 0; wt < 6; ++wt) m = fmaxf(m, acc[wt][r]);
      for (int sh = 1; sh < 16; sh <<= 1) m = fmaxf(m, __shfl_xor(m, sh));
      float s = 0.f;
      #pragma unroll
      for (int wt = 0; wt < 6; ++wt){
        float e = __expf(acc[wt][r] - m);
        bool valid = (wt*16 + (l & 15)) < VV;
        acc[wt][r] = valid ? e : 0.f;
        s += acc[wt][r];
      }
      for (int sh = 1; sh < 16; sh <<= 1) s += __shfl_xor(s, sh);
      int row = v0 + (l >> 4)*4 + r;
      if ((l & 15) == 0){ Sf[oMRS + row] = m; Sf[oISRS + row] = 1.f / s; }
      if (row < VV){
        #pragma unroll
        for (int wt = 0; wt < 6; ++wt) USp[row*96 + wt*16 + (l & 15)] = f2bf(acc[wt][r]);
      }
    }
  }
  __syncthreads();

  // ---------- Ph5b: Et col stats (no logs), wave15 reduces M_s ----------
  {
    int c = tid >> 3, p = tid & 7;
    float mp = bf2f(Up[c*136 + 128 + p]);
    mp = fmaxf(mp, __shfl_xor(mp, 1));
    mp = fmaxf(mp, __shfl_xor(mp, 2));
    mp = fmaxf(mp, __shfl_xor(mp, 4));
    float s = 0.f;
    #pragma unroll
    for (int j = 0; j < 16; ++j){
      int d = p*16 + j;
      float u = bf2f(Up[d*136 + c]);
      if (u > 0.f){
        float e1 = __expf(0.5f * (Sf[oMRT + d] - mp));
        s += (u * e1) * e1;
      }
    }
    s += __shfl_xor(s, 1); s += __shfl_xor(s, 2); s += __shfl_xor(s, 4);
    if (p == 0){ Sf[oMCT + c] = mp; Sf[oISCT + c] = 1.f / s; }
  }
  if (wid == 15){
    float m = (l < 90) ? Sf[oMRS + l] : -3e38f;
    if (l < 26) m = fmaxf(m, Sf[oMRS + 64 + l]);
    for (int sh = 1; sh < 64; sh <<= 1) m = fmaxf(m, __shfl_xor(m, sh));
    if (l == 0) Sf[oSCAL + 8] = m;
  }
  __syncthreads();

  // ---------- Ph6: Es col sums (global-max trick) ----------
  if (tid < 768){
    int v = tid >> 3, p = tid & 7;
    float Ms = Sf[oSCAL + 8];
    float s = 0.f;
    for (int j = 0; j < 12; ++j){
      int w = p*12 + j;
      if (w < VV){
        float u = bf2f(USp[w*96 + v]);
        if (u > 0.f) s += u * __expf(Sf[oMRS + w] - Ms);
      }
    }
    s += __shfl_xor(s, 1); s += __shfl_xor(s, 2); s += __shfl_xor(s, 4);
    if (p == 0) Sf[oISCS + v] = 1.f / fmaxf(s, 1e-30f);
  }
  __syncthreads();

  // ---------- Ph7: M1 (waves 0-7), M2 (waves 8-15) ----------
  if (wid < 8){
    int c0 = wid * 16;
    const s16* G1 = (const s16*)(sm + G1T);
    s16* M1 = (s16*)(sm + M1o);
    int ca = c0 + (l & 15);
    float mctc = Sf[oMCT + ca];
    f32x4 acc[6] = {};
    for (int kk = 0; kk < 4; ++kk){
      int db = kk*32 + (l >> 4) * 8;
      bf16x8 a;
      #pragma unroll
      for (int b = 0; b < 8; ++b){
        float u = bf2f(Up[(db + b)*136 + ca]);
        float val = 0.f;
        if (u > 0.f){
          float e1 = __expf(0.5f * (Sf[oMRT + db + b] - mctc));
          val = (u * e1) * e1;
        }
        a[b] = f2bf(val);
      }
      #pragma unroll
      for (int vt = 0; vt < 6; ++vt){
        bf16x8 bfv = bfrag_ld(G1 + vt*16*136 + kk*32, 136);
        acc[vt] = MFMABF(a, bfv, acc[vt]);
      }
    }
    #pragma unroll
    for (int vt = 0; vt < 6; ++vt){
      int v = vt*16 + (l & 15);
      float cs = (v < VV) ? Sf[oISRS + v] : 0.f;
      #pragma unroll
      for (int r = 0; r < 4; ++r){
        int c = c0 + (l >> 4)*4 + r;
        M1[c*96 + v] = f2bf(acc[vt][r] * Sf[oISCT + c] * cs);
      }
    }
  } else {
    int c0 = (wid - 8) * 16;
    const s16* G2 = (const s16*)(sm + G2T);
    s16* M2 = (s16*)(sm + M2o);
    f32x4 acc[6] = {};
    for (int kk = 0; kk < 4; ++kk){
      bf16x8 a = bfrag_ld(Up + c0*136 + kk*32, 136);
      #pragma unroll
      for (int vt = 0; vt < 6; ++vt){
        bf16x8 bfv = bfrag_ld(G2 + vt*16*136 + kk*32, 136);
        acc[vt] = MFMABF(a, bfv, acc[vt]);
      }
    }
    #pragma unroll
    for (int vt = 0; vt < 6; ++vt){
      int v = vt*16 + (l & 15);
      float cs = (v < VV) ? Sf[oISCS + v] : 0.f;
      #pragma unroll
      for (int r = 0; r < 4; ++r){
        int c = c0 + (l >> 4)*4 + r;
        M2[c*96 + v] = f2bf(acc[vt][r] * Sf[oISRT + c] * cs);
      }
    }
  }
  __syncthreads();

  // ---------- Ph8: z1T / z2T — 48 balanced units (z x wtile x col-quarter) ----------
  for (int pass = 0; pass < 3; ++pass){
    int u = wid + pass*16;          // 0..47
    bool isZ2 = u >= 24;
    int rem = isZ2 ? u - 24 : u;    // 0..23
    int w0 = (rem >> 2) * 16;       // 6 w-tiles
    int cq = rem & 3;               // 4 col-quarters, 2 ct each
    int wa = w0 + (l & 15);
    const s16* Mx = (const s16*)(sm + (isZ2 ? M2o : M1o));
    s16* Z = (s16*)(sm + (isZ2 ? Z2o : Z1o));
    int wr = (wa < VV) ? wa : (VV - 1);
    float e_row = isZ2 ? __expf(Sf[oMRS + wr] - Sf[oSCAL + 8]) : 0.f;   // <= 1
    f32x4 acc[2] = {};
    for (int kk = 0; kk < 3; ++kk){
      int vb = kk*32 + (l >> 4) * 8;
      bf16x8 a;
      if (!isZ2){
        #pragma unroll
        for (int b = 0; b < 8; ++b){
          int v = vb + b;
          a[b] = (v < VV) ? USp[v*96 + wa] : (s16)0;
        }
      } else {
        const s16* up = USp + wr*96 + vb;
        #pragma unroll
        for (int b = 0; b < 8; ++b){
          a[b] = f2bf(bf2f(up[b]) * e_row);
        }
      }
      #pragma unroll
      for (int ct = 0; ct < 2; ++ct){
        bf16x8 bfv = bfrag_ld(Mx + (cq*2 + ct)*16*96 + kk*32, 96);
        acc[ct] = MFMABF(a, bfv, acc[ct]);
      }
    }
    #pragma unroll
    for (int ct = 0; ct < 2; ++ct){
      #pragma unroll
      for (int r = 0; r < 4; ++r){
        int row = w0 + (l >> 4)*4 + r;
        Z[row*136 + (cq*2 + ct)*16 + (l & 15)] = f2bf(acc[ct][r]);
      }
    }
  }
  __syncthreads();

  // ---------- Ph9a: z column sums (1024 threads) ----------
  {
    int col = tid >> 3, zi = (tid >> 2) & 1, p = tid & 3;
    const s16* Z = (const s16*)(sm + (zi ? Z2o : Z1o));
    float s = 0.f;
    for (int j = 0; j < 23; ++j){
      int w = p*23 + j;
      if (w < VV) s += bf2f(Z[w*136 + col]);
    }
    s += __shfl_xor(s, 1); s += __shfl_xor(s, 2);
    if (p == 0){
      float* R = Sf + (zi ? oRED2 : oRED1);
      R[col] = csw[col] * s;
    }
  }
  __syncthreads();
  // ---------- Ph9b: final reductions ----------
  if (wid == 0){
    float s = Sf[oRED1 + l] + Sf[oRED1 + 64 + l];
    for (int sh = 1; sh < 64; sh <<= 1) s += __shfl_xor(s, sh);
    if (l == 0) Sf[oSCAL + 9] = s;
  } else if (wid == 1){
    float s = Sf[oRED2 + l] + Sf[oRED2 + 64 + l];
    for (int sh = 1; sh < 64; sh <<= 1) s += __shfl_xor(s, sh);
    if (l == 0) Sf[oSCAL + 10] = s;
  } else if (wid == 2){
    float s = 0.f;
    #pragma unroll
    for (int j = 0; j < 4; ++j) s += Sf[oX1MV + l*4 + j];
    for (int sh = 1; sh < 64; sh <<= 1) s += __shfl_xor(s, sh);
    if (l == 0) Sf[oSCAL + 11] = s;
  } else if (wid == 3){
    float s = (l < VV) ? Sf[oX2MT + l] : 0.f;
    if (l < 26) s += Sf[oX2MT + 64 + l];
    for (int sh = 1; sh < 64; sh <<= 1) s += __shfl_xor(s, sh);
    if (l == 0) Sf[oSCAL + 12] = s;
  }
  __syncthreads();
  if (tid == 0){
    float m1 = Sf[oSCAL + 11] * (1.f/256.f);
    float m2 = Sf[oSCAL + 12] * (1.f/90.f);
    float zd1 = Sf[oSCAL + 9], zd2 = Sf[oSCAL + 10];
    float bws = bwsum[0];
    float mp1 = (zd1 + 90.f*bws) * (1.f/23040.f);
    float mp2 = (zd2 + 90.f*bws) * (1.f/23040.f);
    {
      float mx = fmaxf(m1, fmaxf(m2, mp1));
      float e0 = __expf(m1-mx), e1 = __expf(m2-mx), e2 = __expf(mp1-mx);
      float inv = 1.f/(e0+e1+e2);
      Sf[oSCAL+0] = e0*inv; Sf[oSCAL+1] = e1*inv; Sf[oSCAL+2] = e2*inv;
    }
    {
      float mx = fmaxf(m2, fmaxf(m1, mp2));
      float e0 = __expf(m2-mx), e1 = __expf(m1-mx), e2 = __expf(mp2-mx);
      float inv = 1.f/(e0+e1+e2);
      Sf[oSCAL+3] = e0*inv; Sf[oSCAL+4] = e1*inv; Sf[oSCAL+5] = e2*inv;
    }
  }
  __syncthreads();

  // ---------- Ph10: proj + fused outputs — 32 units, 2 passes ----------
  {
    float* out1 = outg + (size_t)bid * BTV;
    float* out2 = outg + (size_t)NB * BTV + (size_t)bid * BTV;
    for (int pass = 0; pass < 2; ++pass){
      int u = wid + pass*16;
      bool is2 = u & 1;
      int t0 = (u >> 1) * 16;
      const s16* Zp = (const s16*)(sm + (is2 ? Z2o : Z1o));
      f32x4 acc[6] = {};
      for (int kk = 0; kk < 4; ++kk){
        bf16x8 a = bfrag_ld(WP + t0*128 + kk*32, 128);
        #pragma unroll
        for (int vt = 0; vt < 6; ++vt){
          bf16x8 b = bfrag_ld(Zp + vt*16*136 + kk*32, 136);
          acc[vt] = MFMABF(a, b, acc[vt]);
        }
      }
      const float* xb = is2 ? x2b : x1b;
      float* op = is2 ? out2 : out1;
      float wa = is2 ? Sf[oSCAL+3] : Sf[oSCAL+0];
      float wb = is2 ? Sf[oSCAL+4] : Sf[oSCAL+1];
      float wc = is2 ? Sf[oSCAL+5] : Sf[oSCAL+2];
      #pragma unroll
      for (int r = 0; r < 4; ++r){
        int t = t0 + (l >> 4)*4 + r;
        float bw = bwe[t];
        float crossv = is2 ? Sf[oX1MV + t] : 0.f;
        #pragma unroll
        for (int vt = 0; vt < 6; ++vt){
          int v = vt*16 + (l & 15);
          if (v < VV){
            float cross = is2 ? crossv : Sf[oX2MT + v];
            op[t*VV + v] = wa * xb[t*VV + v] + wb * cross + wc * (acc[vt][r] + bw);
          }
        }
      }
    }
  }
}

} // namespace

extern "C" void kernel_launch(void* const* d_in, const int* in_sizes, int n_in,
                              void* d_out, int out_size, void* d_ws, size_t ws_size,
                              hipStream_t stream)
{
  (void)in_sizes; (void)n_in; (void)out_size; (void)ws_size;
  hipFuncSetAttribute((const void*)stacif_main,
                      hipFuncAttributeMaxDynamicSharedMemorySize, SMEM_BYTES);

  const float* x1 = (const float*)d_in[0];
  const float* x2 = (const float*)d_in[1];
  const float* g_bng = (const float*)d_in[2];
  const float* g_bnb = (const float*)d_in[3];
  const float* g_bnm = (const float*)d_in[4];
  const float* g_bnv = (const float*)d_in[5];
  const float* g_w   = (const float*)d_in[6];
  const float* g_b   = (const float*)d_in[7];
  const float* th_bng = (const float*)d_in[8];
  const float* th_bnb = (const float*)d_in[9];
  const float* th_bnm = (const float*)d_in[10];
  const float* th_bnv = (const float*)d_in[11];
  const float* th_w   = (const float*)d_in[12];
  const float* th_b   = (const float*)d_in[13];
  const float* ph_bng = (const float*)d_in[14];
  const float* ph_bnb = (const float*)d_in[15];
  const float* ph_bnm = (const float*)d_in[16];
  const float* ph_bnv = (const float*)d_in[17];
  const float* ph_w   = (const float*)d_in[18];
  const float* ph_b   = (const float*)d_in[19];
  const float* W_w    = (const float*)d_in[20];
  const float* W_b    = (const float*)d_in[21];
  const float* W_bng  = (const float*)d_in[22];
  const float* W_bnb  = (const float*)d_in[23];
  const float* W_bnm  = (const float*)d_in[24];
  const float* W_bnv  = (const float*)d_in[25];
  char* ws = (char*)d_ws;
  float* out = (float*)d_out;

  prep_weights<<<dim3(256), dim3(256), 0, stream>>>(
      th_w, th_b, th_bng, th_bnb, th_bnm, th_bnv,
      g_w, g_b, g_bng, g_bnb, g_bnm, g_bnv,
      ph_w, ph_b, ph_bng, ph_bnb, ph_bnm, ph_bnv,
      W_w, W_b, W_bng, W_bnb, W_bnm, W_bnv, ws);
  prep_scalars<<<dim3(1), dim3(256), 0, stream>>>(W_w, W_bng, W_bnv, ws);
  stacif_main<<<dim3(NB), dim3(NT), SMEM_BYTES, stream>>>(x1, x2, ws, out);
}